// Round 1
// baseline (1548.134 us; speedup 1.0000x reference)
//
#include <hip/hip_runtime.h>

#define HID 128
#define DNODE 64
#define NNODES 50000
#define NEDGES 600000
#define NGRAPHS 64
#define LN_EPS 1e-5f

// ---------------- encoder: h = LN(ReLU(x @ enc_w + enc_b)) ----------------
__global__ void __launch_bounds__(128) encoder_kernel(
    const float* __restrict__ x, const float* __restrict__ enc_w,
    const float* __restrict__ enc_b, const float* __restrict__ ln_g,
    const float* __restrict__ ln_b, float* __restrict__ A) {
  int node = blockIdx.x;
  int j = threadIdx.x;  // 0..127
  __shared__ float xs[DNODE];
  __shared__ float red[4];
  if (j < DNODE) xs[j] = x[(size_t)node * DNODE + j];
  __syncthreads();
  float acc = enc_b[j];
#pragma unroll
  for (int k = 0; k < DNODE; ++k) acc = fmaf(xs[k], enc_w[k * HID + j], acc);
  acc = fmaxf(acc, 0.f);
  // LayerNorm across 128 threads (2 waves)
  float s = acc, s2 = acc * acc;
#pragma unroll
  for (int off = 32; off; off >>= 1) {
    s += __shfl_down(s, off);
    s2 += __shfl_down(s2, off);
  }
  int lane = j & 63, wid = j >> 6;
  if (lane == 0) { red[wid] = s; red[2 + wid] = s2; }
  __syncthreads();
  float mu = (red[0] + red[1]) * (1.0f / HID);
  float var = (red[2] + red[3]) * (1.0f / HID) - mu * mu;
  float v = (acc - mu) * rsqrtf(var + LN_EPS) * ln_g[j] + ln_b[j];
  A[(size_t)node * HID + j] = v;
}

// ---------------- degree + rsqrt ----------------
__global__ void degree_kernel(const int* __restrict__ dst, float* __restrict__ deg) {
  int e = blockIdx.x * blockDim.x + threadIdx.x;
  if (e < NEDGES) atomicAdd(&deg[dst[e]], 1.0f);
}

__global__ void dis_kernel(const float* __restrict__ deg, float* __restrict__ dis) {
  int i = blockIdx.x * blockDim.x + threadIdx.x;
  if (i < NNODES) dis[i] = rsqrtf(deg[i] + 1.0f);  // deg includes +1 self loop
}

// ---------------- conv: hw = h @ W ; acc = hw*(1/deg) + bias (in place) ----
__global__ void __launch_bounds__(128) conv_kernel(
    const float* __restrict__ Ain, const float* __restrict__ W,
    const float* __restrict__ bias, const float* __restrict__ dis,
    float* __restrict__ B, float* __restrict__ A, int apply_relu) {
  int node = blockIdx.x;
  int j = threadIdx.x;
  __shared__ float hs[HID];
  float hv = Ain[(size_t)node * HID + j];
  if (apply_relu) hv = fmaxf(hv, 0.f);
  hs[j] = hv;
  __syncthreads();
  float acc = 0.f;
#pragma unroll 8
  for (int k = 0; k < HID; ++k) acc = fmaf(hs[k], W[k * HID + j], acc);
  B[(size_t)node * HID + j] = acc;
  float d = dis[node];
  A[(size_t)node * HID + j] = fmaf(acc, d * d, bias[j]);
}

// ---------------- edge scatter: A[dst] += B[src] * dis[src]*dis[dst] -------
__global__ void __launch_bounds__(256) scatter_kernel(
    const int* __restrict__ src, const int* __restrict__ dst,
    const float* __restrict__ dis, const float* __restrict__ B,
    float* __restrict__ A) {
  long long t = (long long)blockIdx.x * blockDim.x + threadIdx.x;
  int e = (int)(t >> 7);
  int j = (int)(t & 127);
  if (e >= NEDGES) return;
  int s = src[e], d = dst[e];
  float enorm = dis[s] * dis[d];
  atomicAdd(&A[(size_t)d * HID + j], B[(size_t)s * HID + j] * enorm);
}

// ---------------- pooling: sums[g] += relu(A[node]); cnts[g] += 1 ----------
__global__ void __launch_bounds__(128) pool_kernel(
    const float* __restrict__ A, const int* __restrict__ batch,
    float* __restrict__ sums, float* __restrict__ cnts) {
  int node = blockIdx.x;
  int j = threadIdx.x;
  int g = batch[node];
  float v = fmaxf(A[(size_t)node * HID + j], 0.f);
  atomicAdd(&sums[g * HID + j], v);
  if (j == 0) atomicAdd(&cnts[g], 1.0f);
}

// ---------------- classifier head ----------------
__global__ void __launch_bounds__(64) cls_kernel(
    const float* __restrict__ sums, const float* __restrict__ cnts,
    const float* __restrict__ c1w, const float* __restrict__ c1b,
    const float* __restrict__ c2w, const float* __restrict__ c2b,
    float* __restrict__ out) {
  int g = blockIdx.x;
  int j = threadIdx.x;  // 0..63
  __shared__ float pooled[HID];
  float inv = 1.0f / fmaxf(cnts[g], 1.0f);
  pooled[j] = sums[g * HID + j] * inv;
  pooled[j + 64] = sums[g * HID + j + 64] * inv;
  __syncthreads();
  float s = c1b[j];
#pragma unroll 8
  for (int k = 0; k < HID; ++k) s = fmaf(pooled[k], c1w[k * 64 + j], s);
  s = fmaxf(s, 0.f) * c2w[j];
#pragma unroll
  for (int off = 32; off; off >>= 1) s += __shfl_down(s, off);
  if (j == 0) out[g] = s + c2b[0];
}

extern "C" void kernel_launch(void* const* d_in, const int* in_sizes, int n_in,
                              void* d_out, int out_size, void* d_ws, size_t ws_size,
                              hipStream_t stream) {
  const float* x = (const float*)d_in[0];
  const int* edge_index = (const int*)d_in[1];
  // d_in[2] edge_attr: unused downstream (edge encoder output discarded)
  const int* batch = (const int*)d_in[3];
  const float* enc_w = (const float*)d_in[4];
  const float* enc_b = (const float*)d_in[5];
  const float* ln_g = (const float*)d_in[6];
  const float* ln_b = (const float*)d_in[7];
  // d_in[8], d_in[9]: edge encoder weights, unused
  const float* conv_ws = (const float*)d_in[10];
  const float* conv_bs = (const float*)d_in[11];
  const float* c1w = (const float*)d_in[12];
  const float* c1b = (const float*)d_in[13];
  const float* c2w = (const float*)d_in[14];
  const float* c2b = (const float*)d_in[15];
  float* out = (float*)d_out;

  float* A = (float*)d_ws;                       // h / acc  [NNODES*HID]
  float* B = A + (size_t)NNODES * HID;           // hw       [NNODES*HID]
  float* deg = B + (size_t)NNODES * HID;         // [NNODES]
  float* dis = deg + NNODES;                     // [NNODES]
  float* sums = dis + NNODES;                    // [NGRAPHS*HID]
  float* cnts = sums + NGRAPHS * HID;            // [NGRAPHS]

  const int* srcp = edge_index;
  const int* dstp = edge_index + NEDGES;

  hipMemsetAsync(deg, 0, NNODES * sizeof(float), stream);
  hipMemsetAsync(sums, 0, (NGRAPHS * HID + NGRAPHS) * sizeof(float), stream);

  encoder_kernel<<<NNODES, 128, 0, stream>>>(x, enc_w, enc_b, ln_g, ln_b, A);
  degree_kernel<<<(NEDGES + 255) / 256, 256, 0, stream>>>(dstp, deg);
  dis_kernel<<<(NNODES + 255) / 256, 256, 0, stream>>>(deg, dis);

  for (int L = 0; L < 3; ++L) {
    conv_kernel<<<NNODES, 128, 0, stream>>>(A, conv_ws + (size_t)L * HID * HID,
                                            conv_bs + (size_t)L * HID, dis, B, A,
                                            L > 0 ? 1 : 0);
    scatter_kernel<<<(int)(((long long)NEDGES * HID) / 256), 256, 0, stream>>>(
        srcp, dstp, dis, B, A);
  }

  pool_kernel<<<NNODES, 128, 0, stream>>>(A, batch, sums, cnts);
  cls_kernel<<<NGRAPHS, 64, 0, stream>>>(sums, cnts, c1w, c1b, c2w, c2b, out);
}

// Round 2
// 480.551 us; speedup vs baseline: 3.2216x; 3.2216x over previous
//
#include <hip/hip_runtime.h>

#define HID 128
#define DNODE 64
#define NNODES 50000
#define NEDGES 600000
#define NGRAPHS 64
#define LN_EPS 1e-5f
#define NPB 8                 // nodes per block in GEMM kernels
#define SCAN_BLK 256
#define NSCAN ((NNODES + SCAN_BLK - 1) / SCAN_BLK)   // 196

// ======== encoder: A = LN(ReLU(x @ enc_w + enc_b)), 8 nodes/block ========
__global__ void __launch_bounds__(128) encoder8_kernel(
    const float* __restrict__ x, const float* __restrict__ enc_w,
    const float* __restrict__ enc_b, const float* __restrict__ ln_g,
    const float* __restrict__ ln_b, float* __restrict__ A) {
  int base = blockIdx.x * NPB;
  int j = threadIdx.x;
  __shared__ float xs[NPB][DNODE];
  __shared__ float hs[NPB][HID];
  __shared__ float smu[NPB], svar[NPB];
  const float* xb = x + (size_t)base * DNODE;
#pragma unroll
  for (int it = 0; it < NPB * DNODE / 128; ++it)
    ((float*)xs)[j + 128 * it] = xb[j + 128 * it];
  __syncthreads();
  float bj = enc_b[j];
  float acc[NPB];
#pragma unroll
  for (int n = 0; n < NPB; ++n) acc[n] = bj;
#pragma unroll 4
  for (int k = 0; k < DNODE; ++k) {
    float wv = enc_w[k * HID + j];
#pragma unroll
    for (int n = 0; n < NPB; ++n) acc[n] = fmaf(xs[n][k], wv, acc[n]);
  }
#pragma unroll
  for (int n = 0; n < NPB; ++n) {
    acc[n] = fmaxf(acc[n], 0.f);
    hs[n][j] = acc[n];
  }
  __syncthreads();
  {  // per-node mean/var: 16 threads per node
    int n = j >> 4, t = j & 15;
    float s = 0.f, s2 = 0.f;
#pragma unroll
    for (int i = 0; i < 8; ++i) {
      float v = hs[n][t + 16 * i];
      s += v; s2 += v * v;
    }
#pragma unroll
    for (int off = 8; off; off >>= 1) {
      s += __shfl_xor(s, off);
      s2 += __shfl_xor(s2, off);
    }
    if (t == 0) { smu[n] = s; svar[n] = s2; }
  }
  __syncthreads();
  float gj = ln_g[j], bbj = ln_b[j];
#pragma unroll
  for (int n = 0; n < NPB; ++n) {
    float mu = smu[n] * (1.0f / HID);
    float var = svar[n] * (1.0f / HID) - mu * mu;
    A[(size_t)(base + n) * HID + j] =
        (acc[n] - mu) * rsqrtf(var + LN_EPS) * gj + bbj;
  }
}

// ======== degree count (int) ========
__global__ void count_kernel(const int* __restrict__ dst, int* __restrict__ degi) {
  int e = blockIdx.x * blockDim.x + threadIdx.x;
  if (e < NEDGES) atomicAdd(&degi[dst[e]], 1);
}

// ======== scan step 1: per-block sums ========
__global__ void __launch_bounds__(SCAN_BLK) blocksum_kernel(
    const int* __restrict__ degi, int* __restrict__ bsum) {
  int i = blockIdx.x * SCAN_BLK + threadIdx.x;
  int v = (i < NNODES) ? degi[i] : 0;
#pragma unroll
  for (int off = 32; off; off >>= 1) v += __shfl_down(v, off);
  __shared__ int wsum[4];
  if ((threadIdx.x & 63) == 0) wsum[threadIdx.x >> 6] = v;
  __syncthreads();
  if (threadIdx.x == 0) bsum[blockIdx.x] = wsum[0] + wsum[1] + wsum[2] + wsum[3];
}

// ======== scan step 2: exclusive scan of block sums (1 block) ========
__global__ void __launch_bounds__(SCAN_BLK) scanb_kernel(
    int* __restrict__ bsum, int* __restrict__ off) {
  __shared__ int s[SCAN_BLK];
  int t = threadIdx.x;
  int v = (t < NSCAN) ? bsum[t] : 0;
  s[t] = v;
  __syncthreads();
  for (int d = 1; d < SCAN_BLK; d <<= 1) {
    int x = (t >= d) ? s[t - d] : 0;
    __syncthreads();
    s[t] += x;
    __syncthreads();
  }
  if (t < NSCAN) bsum[t] = s[t] - v;  // exclusive
  if (t == 0) off[NNODES] = NEDGES;
}

// ======== scan step 3: per-element offsets + cursor + dis ========
__global__ void __launch_bounds__(SCAN_BLK) offsets_kernel(
    const int* __restrict__ degi, const int* __restrict__ bsum,
    int* __restrict__ off, int* __restrict__ cursor, float* __restrict__ dis) {
  int b = blockIdx.x, t = threadIdx.x;
  int i = b * SCAN_BLK + t;
  __shared__ int s[SCAN_BLK];
  int v = (i < NNODES) ? degi[i] : 0;
  s[t] = v;
  __syncthreads();
  for (int d = 1; d < SCAN_BLK; d <<= 1) {
    int x = (t >= d) ? s[t - d] : 0;
    __syncthreads();
    s[t] += x;
    __syncthreads();
  }
  if (i < NNODES) {
    int excl = s[t] - v + bsum[b];
    off[i] = excl;
    cursor[i] = excl;
    dis[i] = rsqrtf((float)v + 1.0f);
  }
}

// ======== CSR fill ========
__global__ void fill_kernel(const int* __restrict__ src, const int* __restrict__ dst,
                            int* __restrict__ cursor, int* __restrict__ elist) {
  int e = blockIdx.x * blockDim.x + threadIdx.x;
  if (e >= NEDGES) return;
  int d = dst[e];
  int p = atomicAdd(&cursor[d], 1);
  elist[p] = src[e];
}

// ======== conv: B = relu?(A) @ W, 8 nodes/block ========
__global__ void __launch_bounds__(128) conv8_kernel(
    const float* __restrict__ Ain, const float* __restrict__ W,
    float* __restrict__ B, int apply_relu) {
  int base = blockIdx.x * NPB;
  int j = threadIdx.x;
  __shared__ float hs[NPB][HID];
#pragma unroll
  for (int n = 0; n < NPB; ++n) {
    float v = Ain[(size_t)(base + n) * HID + j];
    if (apply_relu) v = fmaxf(v, 0.f);
    hs[n][j] = v;
  }
  __syncthreads();
  float acc[NPB];
#pragma unroll
  for (int n = 0; n < NPB; ++n) acc[n] = 0.f;
#pragma unroll 4
  for (int k = 0; k < HID; ++k) {
    float wv = W[k * HID + j];
#pragma unroll
    for (int n = 0; n < NPB; ++n) acc[n] = fmaf(hs[n][k], wv, acc[n]);
  }
#pragma unroll
  for (int n = 0; n < NPB; ++n) B[(size_t)(base + n) * HID + j] = acc[n];
}

// ======== gather: A[n] = bias + B[n]/deg + sum_in B[s]*dis[s]*dis[n] ========
__global__ void __launch_bounds__(128) gather_kernel(
    const int* __restrict__ off, const int* __restrict__ elist,
    const float* __restrict__ dis, const float* __restrict__ bias,
    const float* __restrict__ B, float* __restrict__ A) {
  int n = blockIdx.x;
  int j = threadIdx.x;
  int lo = off[n], hi = off[n + 1];
  float dn = dis[n];
  float acc = 0.f;
  for (int idx = lo; idx < hi; ++idx) {
    int s = elist[idx];
    acc = fmaf(B[(size_t)s * HID + j], dis[s] * dn, acc);
  }
  float self = B[(size_t)n * HID + j];
  A[(size_t)n * HID + j] = fmaf(self, dn * dn, bias[j]) + acc;
}

// ======== graph boundaries (batch is sorted) ========
__global__ void bounds_kernel(const int* __restrict__ batch,
                              int* __restrict__ gstart, int* __restrict__ gend) {
  int i = blockIdx.x * blockDim.x + threadIdx.x;
  if (i >= NNODES) return;
  int g = batch[i];
  if (i == 0 || batch[i - 1] != g) gstart[g] = i;
  if (i == NNODES - 1 || batch[i + 1] != g) gend[g] = i + 1;
}

// ======== pool: 8 chunks per graph, one atomic flush per chunk ========
__global__ void __launch_bounds__(128) pool_kernel(
    const float* __restrict__ A, const int* __restrict__ gstart,
    const int* __restrict__ gend, float* __restrict__ sums) {
  int g = blockIdx.x >> 3, c = blockIdx.x & 7;
  int j = threadIdx.x;
  int s0 = gstart[g], e0 = gend[g];
  int len = e0 - s0;
  int lo = s0 + (int)((long long)len * c / 8);
  int hi = s0 + (int)((long long)len * (c + 1) / 8);
  float acc = 0.f;
  for (int n = lo; n < hi; ++n) acc += fmaxf(A[(size_t)n * HID + j], 0.f);
  atomicAdd(&sums[g * HID + j], acc);
}

// ======== classifier head ========
__global__ void __launch_bounds__(64) cls_kernel(
    const float* __restrict__ sums, const int* __restrict__ gstart,
    const int* __restrict__ gend, const float* __restrict__ c1w,
    const float* __restrict__ c1b, const float* __restrict__ c2w,
    const float* __restrict__ c2b, float* __restrict__ out) {
  int g = blockIdx.x;
  int j = threadIdx.x;  // 0..63
  __shared__ float pooled[HID];
  float cnt = (float)(gend[g] - gstart[g]);
  float inv = 1.0f / fmaxf(cnt, 1.0f);
  pooled[j] = sums[g * HID + j] * inv;
  pooled[j + 64] = sums[g * HID + j + 64] * inv;
  __syncthreads();
  float s = c1b[j];
#pragma unroll 8
  for (int k = 0; k < HID; ++k) s = fmaf(pooled[k], c1w[k * 64 + j], s);
  s = fmaxf(s, 0.f) * c2w[j];
#pragma unroll
  for (int off = 32; off; off >>= 1) s += __shfl_down(s, off);
  if (j == 0) out[g] = s + c2b[0];
}

extern "C" void kernel_launch(void* const* d_in, const int* in_sizes, int n_in,
                              void* d_out, int out_size, void* d_ws, size_t ws_size,
                              hipStream_t stream) {
  const float* x = (const float*)d_in[0];
  const int* edge_index = (const int*)d_in[1];
  const int* batch = (const int*)d_in[3];
  const float* enc_w = (const float*)d_in[4];
  const float* enc_b = (const float*)d_in[5];
  const float* ln_g = (const float*)d_in[6];
  const float* ln_b = (const float*)d_in[7];
  const float* conv_ws = (const float*)d_in[10];
  const float* conv_bs = (const float*)d_in[11];
  const float* c1w = (const float*)d_in[12];
  const float* c1b = (const float*)d_in[13];
  const float* c2w = (const float*)d_in[14];
  const float* c2b = (const float*)d_in[15];
  float* out = (float*)d_out;

  float* A = (float*)d_ws;                      // [NNODES*HID]
  float* B = A + (size_t)NNODES * HID;          // [NNODES*HID]
  int* degi = (int*)(B + (size_t)NNODES * HID); // [NNODES]
  int* off = degi + NNODES;                     // [NNODES+1]
  int* cursor = off + NNODES + 1;               // [NNODES]
  float* dis = (float*)(cursor + NNODES);       // [NNODES]
  int* elist = (int*)(dis + NNODES);            // [NEDGES]
  int* bsum = elist + NEDGES;                   // [SCAN_BLK]
  float* sums = (float*)(bsum + SCAN_BLK);      // [NGRAPHS*HID]
  int* gstart = (int*)(sums + NGRAPHS * HID);   // [NGRAPHS]
  int* gend = gstart + NGRAPHS;                 // [NGRAPHS]

  const int* srcp = edge_index;
  const int* dstp = edge_index + NEDGES;

  hipMemsetAsync(degi, 0, NNODES * sizeof(int), stream);
  hipMemsetAsync(sums, 0, (NGRAPHS * HID + 2 * NGRAPHS) * sizeof(float), stream);

  encoder8_kernel<<<NNODES / NPB, 128, 0, stream>>>(x, enc_w, enc_b, ln_g, ln_b, A);
  count_kernel<<<(NEDGES + 255) / 256, 256, 0, stream>>>(dstp, degi);
  blocksum_kernel<<<NSCAN, SCAN_BLK, 0, stream>>>(degi, bsum);
  scanb_kernel<<<1, SCAN_BLK, 0, stream>>>(bsum, off);
  offsets_kernel<<<NSCAN, SCAN_BLK, 0, stream>>>(degi, bsum, off, cursor, dis);
  fill_kernel<<<(NEDGES + 255) / 256, 256, 0, stream>>>(srcp, dstp, cursor, elist);
  bounds_kernel<<<(NNODES + 255) / 256, 256, 0, stream>>>(batch, gstart, gend);

  for (int L = 0; L < 3; ++L) {
    conv8_kernel<<<NNODES / NPB, 128, 0, stream>>>(
        A, conv_ws + (size_t)L * HID * HID, B, L > 0 ? 1 : 0);
    gather_kernel<<<NNODES, 128, 0, stream>>>(
        off, elist, dis, conv_bs + (size_t)L * HID, B, A);
  }

  pool_kernel<<<NGRAPHS * 8, 128, 0, stream>>>(A, gstart, gend, sums);
  cls_kernel<<<NGRAPHS, 64, 0, stream>>>(sums, gstart, gend, c1w, c1b, c2w, c2b, out);
}

// Round 3
// 412.148 us; speedup vs baseline: 3.7563x; 1.1660x over previous
//
#include <hip/hip_runtime.h>

#define HID 128
#define DNODE 64
#define NNODES 50000
#define NEDGES 600000
#define NGRAPHS 64
#define LN_EPS 1e-5f
#define NPB 8                 // nodes per block in GEMM kernels
#define SCAN_BLK 256
#define NSCAN ((NNODES + SCAN_BLK - 1) / SCAN_BLK)   // 196

// ======== encoder: A = LN(ReLU(x @ enc_w + enc_b)), 8 nodes/block ========
__global__ void __launch_bounds__(128) encoder8_kernel(
    const float* __restrict__ x, const float* __restrict__ enc_w,
    const float* __restrict__ enc_b, const float* __restrict__ ln_g,
    const float* __restrict__ ln_b, float* __restrict__ A) {
  int base = blockIdx.x * NPB;
  int j = threadIdx.x;
  __shared__ float xs[NPB][DNODE];
  __shared__ float hs[NPB][HID];
  __shared__ float smu[NPB], svar[NPB];
  const float* xb = x + (size_t)base * DNODE;
#pragma unroll
  for (int it = 0; it < NPB * DNODE / 128; ++it)
    ((float*)xs)[j + 128 * it] = xb[j + 128 * it];
  __syncthreads();
  float bj = enc_b[j];
  float acc[NPB];
#pragma unroll
  for (int n = 0; n < NPB; ++n) acc[n] = bj;
#pragma unroll 4
  for (int k = 0; k < DNODE; ++k) {
    float wv = enc_w[k * HID + j];
#pragma unroll
    for (int n = 0; n < NPB; ++n) acc[n] = fmaf(xs[n][k], wv, acc[n]);
  }
#pragma unroll
  for (int n = 0; n < NPB; ++n) {
    acc[n] = fmaxf(acc[n], 0.f);
    hs[n][j] = acc[n];
  }
  __syncthreads();
  {  // per-node mean/var: 16 threads per node
    int n = j >> 4, t = j & 15;
    float s = 0.f, s2 = 0.f;
#pragma unroll
    for (int i = 0; i < 8; ++i) {
      float v = hs[n][t + 16 * i];
      s += v; s2 += v * v;
    }
#pragma unroll
    for (int off = 8; off; off >>= 1) {
      s += __shfl_xor(s, off);
      s2 += __shfl_xor(s2, off);
    }
    if (t == 0) { smu[n] = s; svar[n] = s2; }
  }
  __syncthreads();
  float gj = ln_g[j], bbj = ln_b[j];
#pragma unroll
  for (int n = 0; n < NPB; ++n) {
    float mu = smu[n] * (1.0f / HID);
    float var = svar[n] * (1.0f / HID) - mu * mu;
    A[(size_t)(base + n) * HID + j] =
        (acc[n] - mu) * rsqrtf(var + LN_EPS) * gj + bbj;
  }
}

// ======== degree count (int) ========
__global__ void count_kernel(const int* __restrict__ dst, int* __restrict__ degi) {
  int e = blockIdx.x * blockDim.x + threadIdx.x;
  if (e < NEDGES) atomicAdd(&degi[dst[e]], 1);
}

// ======== scan step 1: per-block sums ========
__global__ void __launch_bounds__(SCAN_BLK) blocksum_kernel(
    const int* __restrict__ degi, int* __restrict__ bsum) {
  int i = blockIdx.x * SCAN_BLK + threadIdx.x;
  int v = (i < NNODES) ? degi[i] : 0;
#pragma unroll
  for (int off = 32; off; off >>= 1) v += __shfl_down(v, off);
  __shared__ int wsum[4];
  if ((threadIdx.x & 63) == 0) wsum[threadIdx.x >> 6] = v;
  __syncthreads();
  if (threadIdx.x == 0) bsum[blockIdx.x] = wsum[0] + wsum[1] + wsum[2] + wsum[3];
}

// ======== scan step 2: exclusive scan of block sums (1 block) ========
__global__ void __launch_bounds__(SCAN_BLK) scanb_kernel(
    int* __restrict__ bsum, int* __restrict__ off) {
  __shared__ int s[SCAN_BLK];
  int t = threadIdx.x;
  int v = (t < NSCAN) ? bsum[t] : 0;
  s[t] = v;
  __syncthreads();
  for (int d = 1; d < SCAN_BLK; d <<= 1) {
    int x = (t >= d) ? s[t - d] : 0;
    __syncthreads();
    s[t] += x;
    __syncthreads();
  }
  if (t < NSCAN) bsum[t] = s[t] - v;  // exclusive
  if (t == 0) off[NNODES] = NEDGES;
}

// ======== scan step 3: per-element offsets + cursor + dis ========
__global__ void __launch_bounds__(SCAN_BLK) offsets_kernel(
    const int* __restrict__ degi, const int* __restrict__ bsum,
    int* __restrict__ off, int* __restrict__ cursor, float* __restrict__ dis) {
  int b = blockIdx.x, t = threadIdx.x;
  int i = b * SCAN_BLK + t;
  __shared__ int s[SCAN_BLK];
  int v = (i < NNODES) ? degi[i] : 0;
  s[t] = v;
  __syncthreads();
  for (int d = 1; d < SCAN_BLK; d <<= 1) {
    int x = (t >= d) ? s[t - d] : 0;
    __syncthreads();
    s[t] += x;
    __syncthreads();
  }
  if (i < NNODES) {
    int excl = s[t] - v + bsum[b];
    off[i] = excl;
    cursor[i] = excl;
    dis[i] = rsqrtf((float)v + 1.0f);
  }
}

// ======== CSR fill: pack (src, edge_norm) per slot ========
__global__ void fill_kernel(const int* __restrict__ src, const int* __restrict__ dst,
                            const float* __restrict__ dis,
                            int* __restrict__ cursor, int2* __restrict__ epack) {
  int e = blockIdx.x * blockDim.x + threadIdx.x;
  if (e >= NEDGES) return;
  int s = src[e], d = dst[e];
  int p = atomicAdd(&cursor[d], 1);
  int2 v;
  v.x = s;
  v.y = __float_as_int(dis[s] * dis[d]);
  epack[p] = v;
}

// ======== conv: B = relu?(A) @ W, 8 nodes/block ========
__global__ void __launch_bounds__(128) conv8_kernel(
    const float* __restrict__ Ain, const float* __restrict__ W,
    float* __restrict__ B, int apply_relu) {
  int base = blockIdx.x * NPB;
  int j = threadIdx.x;
  __shared__ float hs[NPB][HID];
#pragma unroll
  for (int n = 0; n < NPB; ++n) {
    float v = Ain[(size_t)(base + n) * HID + j];
    if (apply_relu) v = fmaxf(v, 0.f);
    hs[n][j] = v;
  }
  __syncthreads();
  float acc[NPB];
#pragma unroll
  for (int n = 0; n < NPB; ++n) acc[n] = 0.f;
#pragma unroll 4
  for (int k = 0; k < HID; ++k) {
    float wv = W[k * HID + j];
#pragma unroll
    for (int n = 0; n < NPB; ++n) acc[n] = fmaf(hs[n][k], wv, acc[n]);
  }
#pragma unroll
  for (int n = 0; n < NPB; ++n) B[(size_t)(base + n) * HID + j] = acc[n];
}

// ======== gather: 4 edge slots x 32 threads x float4 per node ========
// A[n] = bias + B[n]/deg + sum_in B[s]*enorm
__global__ void __launch_bounds__(128) gather_kernel(
    const int* __restrict__ off, const int2* __restrict__ epack,
    const float* __restrict__ dis, const float* __restrict__ bias,
    const float* __restrict__ B, float* __restrict__ A) {
  int n = blockIdx.x;
  int t = threadIdx.x;
  int slot = t >> 5;   // 0..3
  int q = t & 31;      // feature quad: features 4q..4q+3
  int lo = off[n], hi = off[n + 1];
  float4 acc = make_float4(0.f, 0.f, 0.f, 0.f);
  for (int idx = lo + slot; idx < hi; idx += 4) {
    int2 e = epack[idx];             // broadcast within slot group
    float w = __int_as_float(e.y);
    float4 v = ((const float4*)(B + (size_t)e.x * HID))[q];
    acc.x = fmaf(v.x, w, acc.x);
    acc.y = fmaf(v.y, w, acc.y);
    acc.z = fmaf(v.z, w, acc.z);
    acc.w = fmaf(v.w, w, acc.w);
  }
  __shared__ float red[4][HID];
  ((float4*)red[slot])[q] = acc;
  __syncthreads();
  int j = t;
  float r = red[0][j] + red[1][j] + red[2][j] + red[3][j];
  float dn = dis[n];
  float self = B[(size_t)n * HID + j];
  A[(size_t)n * HID + j] = fmaf(self, dn * dn, bias[j]) + r;
}

// ======== graph boundaries (batch is sorted) ========
__global__ void bounds_kernel(const int* __restrict__ batch,
                              int* __restrict__ gstart, int* __restrict__ gend) {
  int i = blockIdx.x * blockDim.x + threadIdx.x;
  if (i >= NNODES) return;
  int g = batch[i];
  if (i == 0 || batch[i - 1] != g) gstart[g] = i;
  if (i == NNODES - 1 || batch[i + 1] != g) gend[g] = i + 1;
}

// ======== pool: 8 chunks per graph, one atomic flush per chunk ========
__global__ void __launch_bounds__(128) pool_kernel(
    const float* __restrict__ A, const int* __restrict__ gstart,
    const int* __restrict__ gend, float* __restrict__ sums) {
  int g = blockIdx.x >> 3, c = blockIdx.x & 7;
  int j = threadIdx.x;
  int s0 = gstart[g], e0 = gend[g];
  int len = e0 - s0;
  int lo = s0 + (int)((long long)len * c / 8);
  int hi = s0 + (int)((long long)len * (c + 1) / 8);
  float acc = 0.f;
  for (int n = lo; n < hi; ++n) acc += fmaxf(A[(size_t)n * HID + j], 0.f);
  atomicAdd(&sums[g * HID + j], acc);
}

// ======== classifier head ========
__global__ void __launch_bounds__(64) cls_kernel(
    const float* __restrict__ sums, const int* __restrict__ gstart,
    const int* __restrict__ gend, const float* __restrict__ c1w,
    const float* __restrict__ c1b, const float* __restrict__ c2w,
    const float* __restrict__ c2b, float* __restrict__ out) {
  int g = blockIdx.x;
  int j = threadIdx.x;  // 0..63
  __shared__ float pooled[HID];
  float cnt = (float)(gend[g] - gstart[g]);
  float inv = 1.0f / fmaxf(cnt, 1.0f);
  pooled[j] = sums[g * HID + j] * inv;
  pooled[j + 64] = sums[g * HID + j + 64] * inv;
  __syncthreads();
  float s = c1b[j];
#pragma unroll 8
  for (int k = 0; k < HID; ++k) s = fmaf(pooled[k], c1w[k * 64 + j], s);
  s = fmaxf(s, 0.f) * c2w[j];
#pragma unroll
  for (int off = 32; off; off >>= 1) s += __shfl_down(s, off);
  if (j == 0) out[g] = s + c2b[0];
}

extern "C" void kernel_launch(void* const* d_in, const int* in_sizes, int n_in,
                              void* d_out, int out_size, void* d_ws, size_t ws_size,
                              hipStream_t stream) {
  const float* x = (const float*)d_in[0];
  const int* edge_index = (const int*)d_in[1];
  const int* batch = (const int*)d_in[3];
  const float* enc_w = (const float*)d_in[4];
  const float* enc_b = (const float*)d_in[5];
  const float* ln_g = (const float*)d_in[6];
  const float* ln_b = (const float*)d_in[7];
  const float* conv_ws = (const float*)d_in[10];
  const float* conv_bs = (const float*)d_in[11];
  const float* c1w = (const float*)d_in[12];
  const float* c1b = (const float*)d_in[13];
  const float* c2w = (const float*)d_in[14];
  const float* c2b = (const float*)d_in[15];
  float* out = (float*)d_out;

  float* A = (float*)d_ws;                      // [NNODES*HID]
  float* B = A + (size_t)NNODES * HID;          // [NNODES*HID]
  int* degi = (int*)(B + (size_t)NNODES * HID); // [NNODES]
  int* off = degi + NNODES;                     // [NNODES+1]
  int* cursor = off + NNODES + 1;               // [NNODES]
  float* dis = (float*)(cursor + NNODES);       // [NNODES]
  int2* epack = (int2*)(dis + NNODES);          // [NEDGES] (8B each)
  int* bsum = (int*)(epack + NEDGES);           // [SCAN_BLK]
  float* sums = (float*)(bsum + SCAN_BLK);      // [NGRAPHS*HID]
  int* gstart = (int*)(sums + NGRAPHS * HID);   // [NGRAPHS]
  int* gend = gstart + NGRAPHS;                 // [NGRAPHS]

  const int* srcp = edge_index;
  const int* dstp = edge_index + NEDGES;

  hipMemsetAsync(degi, 0, NNODES * sizeof(int), stream);
  hipMemsetAsync(sums, 0, (NGRAPHS * HID + 2 * NGRAPHS) * sizeof(float), stream);

  encoder8_kernel<<<NNODES / NPB, 128, 0, stream>>>(x, enc_w, enc_b, ln_g, ln_b, A);
  count_kernel<<<(NEDGES + 255) / 256, 256, 0, stream>>>(dstp, degi);
  blocksum_kernel<<<NSCAN, SCAN_BLK, 0, stream>>>(degi, bsum);
  scanb_kernel<<<1, SCAN_BLK, 0, stream>>>(bsum, off);
  offsets_kernel<<<NSCAN, SCAN_BLK, 0, stream>>>(degi, bsum, off, cursor, dis);
  fill_kernel<<<(NEDGES + 255) / 256, 256, 0, stream>>>(srcp, dstp, dis, cursor, epack);
  bounds_kernel<<<(NNODES + 255) / 256, 256, 0, stream>>>(batch, gstart, gend);

  for (int L = 0; L < 3; ++L) {
    conv8_kernel<<<NNODES / NPB, 128, 0, stream>>>(
        A, conv_ws + (size_t)L * HID * HID, B, L > 0 ? 1 : 0);
    gather_kernel<<<NNODES, 128, 0, stream>>>(
        off, epack, dis, conv_bs + (size_t)L * HID, B, A);
  }

  pool_kernel<<<NGRAPHS * 8, 128, 0, stream>>>(A, gstart, gend, sums);
  cls_kernel<<<NGRAPHS, 64, 0, stream>>>(sums, gstart, gend, c1w, c1b, c2w, c2b, out);
}

// Round 4
// 380.685 us; speedup vs baseline: 4.0667x; 1.0826x over previous
//
#include <hip/hip_runtime.h>

#define HID 128
#define DNODE 64
#define NNODES 50000
#define NEDGES 600000
#define NGRAPHS 64
#define LN_EPS 1e-5f
#define NPB 8                 // nodes per block in GEMM kernels
#define SCAN_BLK 256
#define NSCAN ((NNODES + SCAN_BLK - 1) / SCAN_BLK)   // 196
#define PCHUNK 64             // pool chunks per graph

// ======== encoder: A = LN(ReLU(x @ enc_w + enc_b)), 8 nodes/block ========
__global__ void __launch_bounds__(128) encoder8_kernel(
    const float* __restrict__ x, const float* __restrict__ enc_w,
    const float* __restrict__ enc_b, const float* __restrict__ ln_g,
    const float* __restrict__ ln_b, float* __restrict__ A) {
  int base = blockIdx.x * NPB;
  int j = threadIdx.x;
  __shared__ float xs[NPB][DNODE];
  __shared__ float hs[NPB][HID];
  __shared__ float smu[NPB], svar[NPB];
  const float* xb = x + (size_t)base * DNODE;
#pragma unroll
  for (int it = 0; it < NPB * DNODE / 128; ++it)
    ((float*)xs)[j + 128 * it] = xb[j + 128 * it];
  __syncthreads();
  float bj = enc_b[j];
  float acc[NPB];
#pragma unroll
  for (int n = 0; n < NPB; ++n) acc[n] = bj;
#pragma unroll 4
  for (int k = 0; k < DNODE; ++k) {
    float wv = enc_w[k * HID + j];
#pragma unroll
    for (int n = 0; n < NPB; ++n) acc[n] = fmaf(xs[n][k], wv, acc[n]);
  }
#pragma unroll
  for (int n = 0; n < NPB; ++n) {
    acc[n] = fmaxf(acc[n], 0.f);
    hs[n][j] = acc[n];
  }
  __syncthreads();
  {  // per-node mean/var: 16 threads per node
    int n = j >> 4, t = j & 15;
    float s = 0.f, s2 = 0.f;
#pragma unroll
    for (int i = 0; i < 8; ++i) {
      float v = hs[n][t + 16 * i];
      s += v; s2 += v * v;
    }
#pragma unroll
    for (int off = 8; off; off >>= 1) {
      s += __shfl_xor(s, off);
      s2 += __shfl_xor(s2, off);
    }
    if (t == 0) { smu[n] = s; svar[n] = s2; }
  }
  __syncthreads();
  float gj = ln_g[j], bbj = ln_b[j];
#pragma unroll
  for (int n = 0; n < NPB; ++n) {
    float mu = smu[n] * (1.0f / HID);
    float var = svar[n] * (1.0f / HID) - mu * mu;
    A[(size_t)(base + n) * HID + j] =
        (acc[n] - mu) * rsqrtf(var + LN_EPS) * gj + bbj;
  }
}

// ======== degree count (int) ========
__global__ void count_kernel(const int* __restrict__ dst, int* __restrict__ degi) {
  int e = blockIdx.x * blockDim.x + threadIdx.x;
  if (e < NEDGES) atomicAdd(&degi[dst[e]], 1);
}

// ======== scan step 1: per-block sums ========
__global__ void __launch_bounds__(SCAN_BLK) blocksum_kernel(
    const int* __restrict__ degi, int* __restrict__ bsum) {
  int i = blockIdx.x * SCAN_BLK + threadIdx.x;
  int v = (i < NNODES) ? degi[i] : 0;
#pragma unroll
  for (int off = 32; off; off >>= 1) v += __shfl_down(v, off);
  __shared__ int wsum[4];
  if ((threadIdx.x & 63) == 0) wsum[threadIdx.x >> 6] = v;
  __syncthreads();
  if (threadIdx.x == 0) bsum[blockIdx.x] = wsum[0] + wsum[1] + wsum[2] + wsum[3];
}

// ======== scan step 2: exclusive scan of block sums (1 block) ========
__global__ void __launch_bounds__(SCAN_BLK) scanb_kernel(
    int* __restrict__ bsum, int* __restrict__ off) {
  __shared__ int s[SCAN_BLK];
  int t = threadIdx.x;
  int v = (t < NSCAN) ? bsum[t] : 0;
  s[t] = v;
  __syncthreads();
  for (int d = 1; d < SCAN_BLK; d <<= 1) {
    int x = (t >= d) ? s[t - d] : 0;
    __syncthreads();
    s[t] += x;
    __syncthreads();
  }
  if (t < NSCAN) bsum[t] = s[t] - v;  // exclusive
  if (t == 0) off[NNODES] = NEDGES;
}

// ======== scan step 3: per-element offsets + cursor + dis ========
__global__ void __launch_bounds__(SCAN_BLK) offsets_kernel(
    const int* __restrict__ degi, const int* __restrict__ bsum,
    int* __restrict__ off, int* __restrict__ cursor, float* __restrict__ dis) {
  int b = blockIdx.x, t = threadIdx.x;
  int i = b * SCAN_BLK + t;
  __shared__ int s[SCAN_BLK];
  int v = (i < NNODES) ? degi[i] : 0;
  s[t] = v;
  __syncthreads();
  for (int d = 1; d < SCAN_BLK; d <<= 1) {
    int x = (t >= d) ? s[t - d] : 0;
    __syncthreads();
    s[t] += x;
    __syncthreads();
  }
  if (i < NNODES) {
    int excl = s[t] - v + bsum[b];
    off[i] = excl;
    cursor[i] = excl;
    dis[i] = rsqrtf((float)v + 1.0f);
  }
}

// ======== CSR fill: pack (src, edge_norm) per slot ========
__global__ void fill_kernel(const int* __restrict__ src, const int* __restrict__ dst,
                            const float* __restrict__ dis,
                            int* __restrict__ cursor, int2* __restrict__ epack) {
  int e = blockIdx.x * blockDim.x + threadIdx.x;
  if (e >= NEDGES) return;
  int s = src[e], d = dst[e];
  int p = atomicAdd(&cursor[d], 1);
  int2 v;
  v.x = s;
  v.y = __float_as_int(dis[s] * dis[d]);
  epack[p] = v;
}

// ======== conv: B = A @ W, 8 nodes/block (inputs already post-activation) ====
__global__ void __launch_bounds__(128) conv8_kernel(
    const float* __restrict__ Ain, const float* __restrict__ W,
    float* __restrict__ B) {
  int base = blockIdx.x * NPB;
  int j = threadIdx.x;
  __shared__ float hs[NPB][HID];
#pragma unroll
  for (int n = 0; n < NPB; ++n) hs[n][j] = Ain[(size_t)(base + n) * HID + j];
  __syncthreads();
  float acc[NPB];
#pragma unroll
  for (int n = 0; n < NPB; ++n) acc[n] = 0.f;
#pragma unroll 4
  for (int k = 0; k < HID; ++k) {
    float wv = W[k * HID + j];
#pragma unroll
    for (int n = 0; n < NPB; ++n) acc[n] = fmaf(hs[n][k], wv, acc[n]);
  }
#pragma unroll
  for (int n = 0; n < NPB; ++n) B[(size_t)(base + n) * HID + j] = acc[n];
}

// ======== gather: A[n] = relu(bias + B[n]/deg + sum_in B[s]*enorm) ========
// 4 edge slots x 32 threads x float4, 2-way unrolled for ILP
__global__ void __launch_bounds__(128) gather_kernel(
    const int* __restrict__ off, const int2* __restrict__ epack,
    const float* __restrict__ dis, const float* __restrict__ bias,
    const float* __restrict__ B, float* __restrict__ A) {
  int n = blockIdx.x;
  int t = threadIdx.x;
  int slot = t >> 5;   // 0..3
  int q = t & 31;      // feature quad
  int lo = off[n], hi = off[n + 1];
  float4 acc0 = make_float4(0.f, 0.f, 0.f, 0.f);
  float4 acc1 = make_float4(0.f, 0.f, 0.f, 0.f);
  int idx = lo + slot;
  for (; idx + 4 < hi; idx += 8) {
    int2 e0 = epack[idx];
    int2 e1 = epack[idx + 4];
    float w0 = __int_as_float(e0.y);
    float w1 = __int_as_float(e1.y);
    float4 v0 = ((const float4*)(B + (size_t)e0.x * HID))[q];
    float4 v1 = ((const float4*)(B + (size_t)e1.x * HID))[q];
    acc0.x = fmaf(v0.x, w0, acc0.x);
    acc0.y = fmaf(v0.y, w0, acc0.y);
    acc0.z = fmaf(v0.z, w0, acc0.z);
    acc0.w = fmaf(v0.w, w0, acc0.w);
    acc1.x = fmaf(v1.x, w1, acc1.x);
    acc1.y = fmaf(v1.y, w1, acc1.y);
    acc1.z = fmaf(v1.z, w1, acc1.z);
    acc1.w = fmaf(v1.w, w1, acc1.w);
  }
  if (idx < hi) {
    int2 e0 = epack[idx];
    float w0 = __int_as_float(e0.y);
    float4 v0 = ((const float4*)(B + (size_t)e0.x * HID))[q];
    acc0.x = fmaf(v0.x, w0, acc0.x);
    acc0.y = fmaf(v0.y, w0, acc0.y);
    acc0.z = fmaf(v0.z, w0, acc0.z);
    acc0.w = fmaf(v0.w, w0, acc0.w);
  }
  acc0.x += acc1.x; acc0.y += acc1.y; acc0.z += acc1.z; acc0.w += acc1.w;
  __shared__ float red[4][HID];
  ((float4*)red[slot])[q] = acc0;
  __syncthreads();
  int j = t;
  float r = red[0][j] + red[1][j] + red[2][j] + red[3][j];
  float dn = dis[n];
  float self = B[(size_t)n * HID + j];
  A[(size_t)n * HID + j] = fmaxf(fmaf(self, dn * dn, bias[j]) + r, 0.f);
}

// ======== graph boundaries (batch is sorted) ========
__global__ void bounds_kernel(const int* __restrict__ batch,
                              int* __restrict__ gstart, int* __restrict__ gend) {
  int i = blockIdx.x * blockDim.x + threadIdx.x;
  if (i >= NNODES) return;
  int g = batch[i];
  if (i == 0 || batch[i - 1] != g) gstart[g] = i;
  if (i == NNODES - 1 || batch[i + 1] != g) gend[g] = i + 1;
}

// ======== pool: 64 chunks per graph (A already post-relu) ========
__global__ void __launch_bounds__(128) pool_kernel(
    const float* __restrict__ A, const int* __restrict__ gstart,
    const int* __restrict__ gend, float* __restrict__ sums) {
  int g = blockIdx.x >> 6, c = blockIdx.x & (PCHUNK - 1);
  int j = threadIdx.x;
  int s0 = gstart[g], e0 = gend[g];
  int len = e0 - s0;
  int lo = s0 + (int)((long long)len * c / PCHUNK);
  int hi = s0 + (int)((long long)len * (c + 1) / PCHUNK);
  float acc = 0.f;
  for (int n = lo; n < hi; ++n) acc += A[(size_t)n * HID + j];
  if (acc != 0.f || lo < hi) atomicAdd(&sums[g * HID + j], acc);
}

// ======== classifier head ========
__global__ void __launch_bounds__(64) cls_kernel(
    const float* __restrict__ sums, const int* __restrict__ gstart,
    const int* __restrict__ gend, const float* __restrict__ c1w,
    const float* __restrict__ c1b, const float* __restrict__ c2w,
    const float* __restrict__ c2b, float* __restrict__ out) {
  int g = blockIdx.x;
  int j = threadIdx.x;  // 0..63
  __shared__ float pooled[HID];
  float cnt = (float)(gend[g] - gstart[g]);
  float inv = 1.0f / fmaxf(cnt, 1.0f);
  pooled[j] = sums[g * HID + j] * inv;
  pooled[j + 64] = sums[g * HID + j + 64] * inv;
  __syncthreads();
  float s = c1b[j];
#pragma unroll 8
  for (int k = 0; k < HID; ++k) s = fmaf(pooled[k], c1w[k * 64 + j], s);
  s = fmaxf(s, 0.f) * c2w[j];
#pragma unroll
  for (int off = 32; off; off >>= 1) s += __shfl_down(s, off);
  if (j == 0) out[g] = s + c2b[0];
}

extern "C" void kernel_launch(void* const* d_in, const int* in_sizes, int n_in,
                              void* d_out, int out_size, void* d_ws, size_t ws_size,
                              hipStream_t stream) {
  const float* x = (const float*)d_in[0];
  const int* edge_index = (const int*)d_in[1];
  const int* batch = (const int*)d_in[3];
  const float* enc_w = (const float*)d_in[4];
  const float* enc_b = (const float*)d_in[5];
  const float* ln_g = (const float*)d_in[6];
  const float* ln_b = (const float*)d_in[7];
  const float* conv_ws = (const float*)d_in[10];
  const float* conv_bs = (const float*)d_in[11];
  const float* c1w = (const float*)d_in[12];
  const float* c1b = (const float*)d_in[13];
  const float* c2w = (const float*)d_in[14];
  const float* c2b = (const float*)d_in[15];
  float* out = (float*)d_out;

  float* A = (float*)d_ws;                      // [NNODES*HID]
  float* B = A + (size_t)NNODES * HID;          // [NNODES*HID]
  int* degi = (int*)(B + (size_t)NNODES * HID); // [NNODES]
  int* off = degi + NNODES;                     // [NNODES+1]
  int* cursor = off + NNODES + 1;               // [NNODES]
  float* dis = (float*)(cursor + NNODES);       // [NNODES]
  int2* epack = (int2*)(dis + NNODES);          // [NEDGES] (8B each)
  int* bsum = (int*)(epack + NEDGES);           // [SCAN_BLK]
  float* sums = (float*)(bsum + SCAN_BLK);      // [NGRAPHS*HID]
  int* gstart = (int*)(sums + NGRAPHS * HID);   // [NGRAPHS]
  int* gend = gstart + NGRAPHS;                 // [NGRAPHS]

  const int* srcp = edge_index;
  const int* dstp = edge_index + NEDGES;

  hipMemsetAsync(degi, 0, NNODES * sizeof(int), stream);
  hipMemsetAsync(sums, 0, (NGRAPHS * HID + 2 * NGRAPHS) * sizeof(float), stream);

  encoder8_kernel<<<NNODES / NPB, 128, 0, stream>>>(x, enc_w, enc_b, ln_g, ln_b, A);
  count_kernel<<<(NEDGES + 255) / 256, 256, 0, stream>>>(dstp, degi);
  blocksum_kernel<<<NSCAN, SCAN_BLK, 0, stream>>>(degi, bsum);
  scanb_kernel<<<1, SCAN_BLK, 0, stream>>>(bsum, off);
  offsets_kernel<<<NSCAN, SCAN_BLK, 0, stream>>>(degi, bsum, off, cursor, dis);
  fill_kernel<<<(NEDGES + 255) / 256, 256, 0, stream>>>(srcp, dstp, dis, cursor, epack);
  bounds_kernel<<<(NNODES + 255) / 256, 256, 0, stream>>>(batch, gstart, gend);

  for (int L = 0; L < 3; ++L) {
    conv8_kernel<<<NNODES / NPB, 128, 0, stream>>>(
        A, conv_ws + (size_t)L * HID * HID, B);
    gather_kernel<<<NNODES, 128, 0, stream>>>(
        off, epack, dis, conv_bs + (size_t)L * HID, B, A);
  }

  pool_kernel<<<NGRAPHS * PCHUNK, 128, 0, stream>>>(A, gstart, gend, sums);
  cls_kernel<<<NGRAPHS, 64, 0, stream>>>(sums, gstart, gend, c1w, c1b, c2w, c2b, out);
}

// Round 5
// 264.904 us; speedup vs baseline: 5.8441x; 1.4371x over previous
//
#include <hip/hip_runtime.h>

#define HID 128
#define DNODE 64
#define NNODES 50000
#define NEDGES 600000
#define NGRAPHS 64
#define LN_EPS 1e-5f
#define NPB 8
#define SCAN_BLK 256
#define NSCAN ((NNODES + SCAN_BLK - 1) / SCAN_BLK)   // 196
#define PCHUNK 64

typedef __attribute__((ext_vector_type(8))) short bf16x8;
typedef __attribute__((ext_vector_type(8))) unsigned short u16x8;
typedef __attribute__((ext_vector_type(4))) float f32x4;

static __device__ __forceinline__ unsigned short f2bf(float f) {
  unsigned int u = __float_as_uint(f);
  u += 0x7fffu + ((u >> 16) & 1u);   // RNE
  return (unsigned short)(u >> 16);
}
static __device__ __forceinline__ float bf2f(unsigned short h) {
  return __uint_as_float(((unsigned int)h) << 16);
}

// ======== encoder: Abf = bf16(LN(ReLU(x @ enc_w + enc_b))), 8 nodes/block ====
__global__ void __launch_bounds__(128) encoder8_kernel(
    const float* __restrict__ x, const float* __restrict__ enc_w,
    const float* __restrict__ enc_b, const float* __restrict__ ln_g,
    const float* __restrict__ ln_b, unsigned short* __restrict__ Abf) {
  int base = blockIdx.x * NPB;
  int j = threadIdx.x;
  __shared__ float xs[NPB][DNODE];
  __shared__ float hs[NPB][HID];
  __shared__ float smu[NPB], svar[NPB];
  const float* xb = x + (size_t)base * DNODE;
#pragma unroll
  for (int it = 0; it < NPB * DNODE / 128; ++it)
    ((float*)xs)[j + 128 * it] = xb[j + 128 * it];
  __syncthreads();
  float bj = enc_b[j];
  float acc[NPB];
#pragma unroll
  for (int n = 0; n < NPB; ++n) acc[n] = bj;
#pragma unroll 4
  for (int k = 0; k < DNODE; ++k) {
    float wv = enc_w[k * HID + j];
#pragma unroll
    for (int n = 0; n < NPB; ++n) acc[n] = fmaf(xs[n][k], wv, acc[n]);
  }
#pragma unroll
  for (int n = 0; n < NPB; ++n) {
    acc[n] = fmaxf(acc[n], 0.f);
    hs[n][j] = acc[n];
  }
  __syncthreads();
  {
    int n = j >> 4, t = j & 15;
    float s = 0.f, s2 = 0.f;
#pragma unroll
    for (int i = 0; i < 8; ++i) {
      float v = hs[n][t + 16 * i];
      s += v; s2 += v * v;
    }
#pragma unroll
    for (int off = 8; off; off >>= 1) {
      s += __shfl_xor(s, off);
      s2 += __shfl_xor(s2, off);
    }
    if (t == 0) { smu[n] = s; svar[n] = s2; }
  }
  __syncthreads();
  float gj = ln_g[j], bbj = ln_b[j];
#pragma unroll
  for (int n = 0; n < NPB; ++n) {
    float mu = smu[n] * (1.0f / HID);
    float var = svar[n] * (1.0f / HID) - mu * mu;
    Abf[(size_t)(base + n) * HID + j] =
        f2bf((acc[n] - mu) * rsqrtf(var + LN_EPS) * gj + bbj);
  }
}

// ======== pack conv weights into MFMA fragment order (bf16) ========
// Wp[layer][((nt*4+kk)*64+lane)*8+i] = W[layer][kk*32+(lane>>4)*8+i][nt*16+(lane&15)]
__global__ void packw_kernel(const float* __restrict__ W, unsigned short* __restrict__ Wp) {
  int t = blockIdx.x * 256 + threadIdx.x;
  if (t >= 3 * 16384) return;
  int layer = t >> 14;
  int rem = t & 16383;
  int i = rem & 7;
  int lane = (rem >> 3) & 63;
  int kk = (rem >> 9) & 3;
  int nt = (rem >> 11) & 7;
  int k = kk * 32 + (lane >> 4) * 8 + i;
  int n = nt * 16 + (lane & 15);
  Wp[t] = f2bf(W[((size_t)layer * HID + k) * HID + n]);
}

// ======== degree count ========
__global__ void count_kernel(const int* __restrict__ dst, int* __restrict__ degi) {
  int e = blockIdx.x * blockDim.x + threadIdx.x;
  if (e < NEDGES) atomicAdd(&degi[dst[e]], 1);
}

__global__ void __launch_bounds__(SCAN_BLK) blocksum_kernel(
    const int* __restrict__ degi, int* __restrict__ bsum) {
  int i = blockIdx.x * SCAN_BLK + threadIdx.x;
  int v = (i < NNODES) ? degi[i] : 0;
#pragma unroll
  for (int off = 32; off; off >>= 1) v += __shfl_down(v, off);
  __shared__ int wsum[4];
  if ((threadIdx.x & 63) == 0) wsum[threadIdx.x >> 6] = v;
  __syncthreads();
  if (threadIdx.x == 0) bsum[blockIdx.x] = wsum[0] + wsum[1] + wsum[2] + wsum[3];
}

__global__ void __launch_bounds__(SCAN_BLK) scanb_kernel(
    int* __restrict__ bsum, int* __restrict__ off) {
  __shared__ int s[SCAN_BLK];
  int t = threadIdx.x;
  int v = (t < NSCAN) ? bsum[t] : 0;
  s[t] = v;
  __syncthreads();
  for (int d = 1; d < SCAN_BLK; d <<= 1) {
    int x = (t >= d) ? s[t - d] : 0;
    __syncthreads();
    s[t] += x;
    __syncthreads();
  }
  if (t < NSCAN) bsum[t] = s[t] - v;
  if (t == 0) off[NNODES] = NEDGES;
}

__global__ void __launch_bounds__(SCAN_BLK) offsets_kernel(
    const int* __restrict__ degi, const int* __restrict__ bsum,
    int* __restrict__ off, int* __restrict__ cursor, float* __restrict__ dis) {
  int b = blockIdx.x, t = threadIdx.x;
  int i = b * SCAN_BLK + t;
  __shared__ int s[SCAN_BLK];
  int v = (i < NNODES) ? degi[i] : 0;
  s[t] = v;
  __syncthreads();
  for (int d = 1; d < SCAN_BLK; d <<= 1) {
    int x = (t >= d) ? s[t - d] : 0;
    __syncthreads();
    s[t] += x;
    __syncthreads();
  }
  if (i < NNODES) {
    int excl = s[t] - v + bsum[b];
    off[i] = excl;
    cursor[i] = excl;
    dis[i] = rsqrtf((float)v + 1.0f);
  }
}

__global__ void fill_kernel(const int* __restrict__ src, const int* __restrict__ dst,
                            const float* __restrict__ dis,
                            int* __restrict__ cursor, int2* __restrict__ epack) {
  int e = blockIdx.x * blockDim.x + threadIdx.x;
  if (e >= NEDGES) return;
  int s = src[e], d = dst[e];
  int p = atomicAdd(&cursor[d], 1);
  int2 v;
  v.x = s;
  v.y = __float_as_int(dis[s] * dis[d]);
  epack[p] = v;
}

// ======== conv via MFMA: Bbf = bf16(Abf @ W), 64 rows/block (4 waves) ========
__global__ void __launch_bounds__(256) convm_kernel(
    const unsigned short* __restrict__ Abf, const unsigned short* __restrict__ Wp,
    unsigned short* __restrict__ Bbf) {
  int wave = threadIdx.x >> 6;
  int lane = threadIdx.x & 63;
  int base = blockIdx.x * 64 + wave * 16;
  int l15 = lane & 15, hi = lane >> 4;
  int row = base + l15;
  int rowc = row < NNODES ? row : NNODES - 1;
  bf16x8 a[4];
#pragma unroll
  for (int kk = 0; kk < 4; ++kk)
    a[kk] = *(const bf16x8*)(Abf + (size_t)rowc * HID + kk * 32 + hi * 8);
  f32x4 acc[8];
#pragma unroll
  for (int nt = 0; nt < 8; ++nt) acc[nt] = (f32x4)(0.f);
#pragma unroll
  for (int kk = 0; kk < 4; ++kk) {
#pragma unroll
    for (int nt = 0; nt < 8; ++nt) {
      bf16x8 w = *(const bf16x8*)(Wp + (((nt * 4 + kk) * 64 + lane) << 3));
      acc[nt] = __builtin_amdgcn_mfma_f32_16x16x32_bf16(a[kk], w, acc[nt], 0, 0, 0);
    }
  }
#pragma unroll
  for (int nt = 0; nt < 8; ++nt) {
#pragma unroll
    for (int r = 0; r < 4; ++r) {
      int orow = base + hi * 4 + r;
      if (orow < NNODES)
        Bbf[(size_t)orow * HID + nt * 16 + l15] = f2bf(acc[nt][r]);
    }
  }
}

// ======== gather: Abf[n] = bf16(relu(bias + B[n]/deg + sum_in B[s]*enorm)) ====
// 8 edge slots x 16 threads x 8 bf16 features, 2-way unrolled
__global__ void __launch_bounds__(128) gather_kernel(
    const int* __restrict__ off, const int2* __restrict__ epack,
    const float* __restrict__ dis, const float* __restrict__ bias,
    const unsigned short* __restrict__ Bbf, unsigned short* __restrict__ Abf) {
  int n = blockIdx.x;
  int t = threadIdx.x;
  int slot = t >> 4;   // 0..7
  int p = t & 15;      // feature octet
  int lo = off[n], hi = off[n + 1];
  float acc0[8], acc1[8];
#pragma unroll
  for (int i = 0; i < 8; ++i) { acc0[i] = 0.f; acc1[i] = 0.f; }
  int idx = lo + slot;
  for (; idx + 8 < hi; idx += 16) {
    int2 e0 = epack[idx];
    int2 e1 = epack[idx + 8];
    float w0 = __int_as_float(e0.y);
    float w1 = __int_as_float(e1.y);
    u16x8 v0 = *(const u16x8*)(Bbf + (size_t)e0.x * HID + p * 8);
    u16x8 v1 = *(const u16x8*)(Bbf + (size_t)e1.x * HID + p * 8);
#pragma unroll
    for (int i = 0; i < 8; ++i) acc0[i] = fmaf(bf2f(v0[i]), w0, acc0[i]);
#pragma unroll
    for (int i = 0; i < 8; ++i) acc1[i] = fmaf(bf2f(v1[i]), w1, acc1[i]);
  }
  if (idx < hi) {
    int2 e0 = epack[idx];
    float w0 = __int_as_float(e0.y);
    u16x8 v0 = *(const u16x8*)(Bbf + (size_t)e0.x * HID + p * 8);
#pragma unroll
    for (int i = 0; i < 8; ++i) acc0[i] = fmaf(bf2f(v0[i]), w0, acc0[i]);
  }
  __shared__ float red[8][HID];
#pragma unroll
  for (int i = 0; i < 8; ++i) red[slot][p * 8 + i] = acc0[i] + acc1[i];
  __syncthreads();
  int j = t;
  float r = 0.f;
#pragma unroll
  for (int s = 0; s < 8; ++s) r += red[s][j];
  float dn = dis[n];
  float self = bf2f(Bbf[(size_t)n * HID + j]);
  float v = fmaxf(fmaf(self, dn * dn, bias[j]) + r, 0.f);
  Abf[(size_t)n * HID + j] = f2bf(v);
}

// ======== graph boundaries ========
__global__ void bounds_kernel(const int* __restrict__ batch,
                              int* __restrict__ gstart, int* __restrict__ gend) {
  int i = blockIdx.x * blockDim.x + threadIdx.x;
  if (i >= NNODES) return;
  int g = batch[i];
  if (i == 0 || batch[i - 1] != g) gstart[g] = i;
  if (i == NNODES - 1 || batch[i + 1] != g) gend[g] = i + 1;
}

// ======== pool ========
__global__ void __launch_bounds__(128) pool_kernel(
    const unsigned short* __restrict__ Abf, const int* __restrict__ gstart,
    const int* __restrict__ gend, float* __restrict__ sums) {
  int g = blockIdx.x >> 6, c = blockIdx.x & (PCHUNK - 1);
  int j = threadIdx.x;
  int s0 = gstart[g], e0 = gend[g];
  int len = e0 - s0;
  int lo = s0 + (int)((long long)len * c / PCHUNK);
  int hi = s0 + (int)((long long)len * (c + 1) / PCHUNK);
  float acc = 0.f;
  for (int n = lo; n < hi; ++n) acc += bf2f(Abf[(size_t)n * HID + j]);
  if (lo < hi) atomicAdd(&sums[g * HID + j], acc);
}

// ======== classifier head ========
__global__ void __launch_bounds__(64) cls_kernel(
    const float* __restrict__ sums, const int* __restrict__ gstart,
    const int* __restrict__ gend, const float* __restrict__ c1w,
    const float* __restrict__ c1b, const float* __restrict__ c2w,
    const float* __restrict__ c2b, float* __restrict__ out) {
  int g = blockIdx.x;
  int j = threadIdx.x;
  __shared__ float pooled[HID];
  float cnt = (float)(gend[g] - gstart[g]);
  float inv = 1.0f / fmaxf(cnt, 1.0f);
  pooled[j] = sums[g * HID + j] * inv;
  pooled[j + 64] = sums[g * HID + j + 64] * inv;
  __syncthreads();
  float s = c1b[j];
#pragma unroll 8
  for (int k = 0; k < HID; ++k) s = fmaf(pooled[k], c1w[k * 64 + j], s);
  s = fmaxf(s, 0.f) * c2w[j];
#pragma unroll
  for (int off = 32; off; off >>= 1) s += __shfl_down(s, off);
  if (j == 0) out[g] = s + c2b[0];
}

extern "C" void kernel_launch(void* const* d_in, const int* in_sizes, int n_in,
                              void* d_out, int out_size, void* d_ws, size_t ws_size,
                              hipStream_t stream) {
  const float* x = (const float*)d_in[0];
  const int* edge_index = (const int*)d_in[1];
  const int* batch = (const int*)d_in[3];
  const float* enc_w = (const float*)d_in[4];
  const float* enc_b = (const float*)d_in[5];
  const float* ln_g = (const float*)d_in[6];
  const float* ln_b = (const float*)d_in[7];
  const float* conv_ws = (const float*)d_in[10];
  const float* conv_bs = (const float*)d_in[11];
  const float* c1w = (const float*)d_in[12];
  const float* c1b = (const float*)d_in[13];
  const float* c2w = (const float*)d_in[14];
  const float* c2b = (const float*)d_in[15];
  float* out = (float*)d_out;

  unsigned short* Abf = (unsigned short*)d_ws;        // [NNODES*HID] bf16
  unsigned short* Bbf = Abf + (size_t)NNODES * HID;   // [NNODES*HID] bf16
  unsigned short* Wp = Bbf + (size_t)NNODES * HID;    // [3*16384] bf16
  int2* epack = (int2*)(Wp + 3 * 16384);              // [NEDGES]
  int* degi = (int*)(epack + NEDGES);                 // [NNODES]
  int* off = degi + NNODES;                           // [NNODES+1]
  int* cursor = off + NNODES + 1;                     // [NNODES]
  float* dis = (float*)(cursor + NNODES);             // [NNODES]
  int* bsum = (int*)(dis + NNODES);                   // [SCAN_BLK]
  float* sums = (float*)(bsum + SCAN_BLK);            // [NGRAPHS*HID]
  int* gstart = (int*)(sums + NGRAPHS * HID);         // [NGRAPHS]
  int* gend = gstart + NGRAPHS;                       // [NGRAPHS]

  const int* srcp = edge_index;
  const int* dstp = edge_index + NEDGES;

  hipMemsetAsync(degi, 0, NNODES * sizeof(int), stream);
  hipMemsetAsync(sums, 0, (NGRAPHS * HID + 2 * NGRAPHS) * sizeof(float), stream);

  packw_kernel<<<(3 * 16384 + 255) / 256, 256, 0, stream>>>(conv_ws, Wp);
  encoder8_kernel<<<NNODES / NPB, 128, 0, stream>>>(x, enc_w, enc_b, ln_g, ln_b, Abf);
  count_kernel<<<(NEDGES + 255) / 256, 256, 0, stream>>>(dstp, degi);
  blocksum_kernel<<<NSCAN, SCAN_BLK, 0, stream>>>(degi, bsum);
  scanb_kernel<<<1, SCAN_BLK, 0, stream>>>(bsum, off);
  offsets_kernel<<<NSCAN, SCAN_BLK, 0, stream>>>(degi, bsum, off, cursor, dis);
  fill_kernel<<<(NEDGES + 255) / 256, 256, 0, stream>>>(srcp, dstp, dis, cursor, epack);
  bounds_kernel<<<(NNODES + 255) / 256, 256, 0, stream>>>(batch, gstart, gend);

  for (int L = 0; L < 3; ++L) {
    convm_kernel<<<(NNODES + 63) / 64, 256, 0, stream>>>(Abf, Wp + (size_t)L * 16384, Bbf);
    gather_kernel<<<NNODES, 128, 0, stream>>>(
        off, epack, dis, conv_bs + (size_t)L * HID, Bbf, Abf);
  }

  pool_kernel<<<NGRAPHS * PCHUNK, 128, 0, stream>>>(Abf, gstart, gend, sums);
  cls_kernel<<<NGRAPHS, 64, 0, stream>>>(sums, gstart, gend, c1w, c1b, c2w, c2b, out);
}

// Round 6
// 237.916 us; speedup vs baseline: 6.5071x; 1.1134x over previous
//
#include <hip/hip_runtime.h>

#define HID 128
#define DNODE 64
#define NNODES 50000
#define NEDGES 600000
#define NGRAPHS 64
#define LN_EPS 1e-5f
#define SCAN_BLK 256
#define NSCAN ((NNODES + SCAN_BLK - 1) / SCAN_BLK)   // 196
#define PCHUNK 64

#define ENC_BLKS 3125                 // 16 nodes/block
#define CNT_BLKS ((NEDGES + 255) / 256)   // 2344
#define BND_BLKS ((NNODES + 255) / 256)   // 196
#define PKW_BLKS (3 * 16384 / 256)        // 192

typedef __attribute__((ext_vector_type(8))) short bf16x8;
typedef __attribute__((ext_vector_type(8))) unsigned short u16x8;
typedef __attribute__((ext_vector_type(4))) float f32x4;

static __device__ __forceinline__ unsigned short f2bf(float f) {
  unsigned int u = __float_as_uint(f);
  u += 0x7fffu + ((u >> 16) & 1u);   // RNE
  return (unsigned short)(u >> 16);
}
static __device__ __forceinline__ float bf2f(unsigned short h) {
  return __uint_as_float(((unsigned int)h) << 16);
}

// ======== fused prep: encoder | edge-count | graph-bounds | weight-pack ====
__global__ void __launch_bounds__(256) prep_kernel(
    const float* __restrict__ x, const float* __restrict__ enc_w,
    const float* __restrict__ enc_b, const float* __restrict__ ln_g,
    const float* __restrict__ ln_b, unsigned short* __restrict__ Abf,
    const int* __restrict__ dst, int* __restrict__ degi,
    const int* __restrict__ batch, int* __restrict__ gstart,
    int* __restrict__ gend, const float* __restrict__ W,
    unsigned short* __restrict__ Wp) {
  int b = blockIdx.x;
  if (b < ENC_BLKS) {
    // encoder: 16 nodes/block (2 half-blocks of 8)
    __shared__ float xs[2][8][DNODE];
    __shared__ float hs[2][8][HID];
    __shared__ float smu[2][8], svar[2][8];
    int sub = threadIdx.x >> 7;          // 0/1
    int j = threadIdx.x & 127;
    int base = b * 16 + sub * 8;
    const float* xb = x + (size_t)base * DNODE;
#pragma unroll
    for (int it = 0; it < 4; ++it)
      ((float*)xs[sub])[j + 128 * it] = xb[j + 128 * it];
    __syncthreads();
    float bj = enc_b[j];
    float acc[8];
#pragma unroll
    for (int n = 0; n < 8; ++n) acc[n] = bj;
#pragma unroll 4
    for (int k = 0; k < DNODE; ++k) {
      float wv = enc_w[k * HID + j];
#pragma unroll
      for (int n = 0; n < 8; ++n) acc[n] = fmaf(xs[sub][n][k], wv, acc[n]);
    }
#pragma unroll
    for (int n = 0; n < 8; ++n) {
      acc[n] = fmaxf(acc[n], 0.f);
      hs[sub][n][j] = acc[n];
    }
    __syncthreads();
    {
      int n = j >> 4, t = j & 15;
      float s = 0.f, s2 = 0.f;
#pragma unroll
      for (int i = 0; i < 8; ++i) {
        float v = hs[sub][n][t + 16 * i];
        s += v; s2 += v * v;
      }
#pragma unroll
      for (int off = 8; off; off >>= 1) {
        s += __shfl_xor(s, off);
        s2 += __shfl_xor(s2, off);
      }
      if (t == 0) { smu[sub][n] = s; svar[sub][n] = s2; }
    }
    __syncthreads();
    float gj = ln_g[j], bbj = ln_b[j];
#pragma unroll
    for (int n = 0; n < 8; ++n) {
      float mu = smu[sub][n] * (1.0f / HID);
      float var = svar[sub][n] * (1.0f / HID) - mu * mu;
      Abf[(size_t)(base + n) * HID + j] =
          f2bf((acc[n] - mu) * rsqrtf(var + LN_EPS) * gj + bbj);
    }
  } else if (b < ENC_BLKS + CNT_BLKS) {
    int e = (b - ENC_BLKS) * 256 + threadIdx.x;
    if (e < NEDGES) atomicAdd(&degi[dst[e]], 1);
  } else if (b < ENC_BLKS + CNT_BLKS + BND_BLKS) {
    int i = (b - ENC_BLKS - CNT_BLKS) * 256 + threadIdx.x;
    if (i < NNODES) {
      int g = batch[i];
      if (i == 0 || batch[i - 1] != g) gstart[g] = i;
      if (i == NNODES - 1 || batch[i + 1] != g) gend[g] = i + 1;
    }
  } else {
    int t = (b - ENC_BLKS - CNT_BLKS - BND_BLKS) * 256 + threadIdx.x;
    if (t < 3 * 16384) {
      int i = t & 7;
      int lane = (t >> 3) & 63;
      int kk = (t >> 9) & 3;
      int nt = (t >> 11) & 7;
      int layer = t >> 14;
      int k = kk * 32 + (lane >> 4) * 8 + i;
      int n = nt * 16 + (lane & 15);
      Wp[t] = f2bf(W[((size_t)layer * HID + k) * HID + n]);
    }
  }
}

// ======== scan step 1: per-block sums ========
__global__ void __launch_bounds__(SCAN_BLK) blocksum_kernel(
    const int* __restrict__ degi, int* __restrict__ bsum) {
  int i = blockIdx.x * SCAN_BLK + threadIdx.x;
  int v = (i < NNODES) ? degi[i] : 0;
#pragma unroll
  for (int off = 32; off; off >>= 1) v += __shfl_down(v, off);
  __shared__ int wsum[4];
  if ((threadIdx.x & 63) == 0) wsum[threadIdx.x >> 6] = v;
  __syncthreads();
  if (threadIdx.x == 0) bsum[blockIdx.x] = wsum[0] + wsum[1] + wsum[2] + wsum[3];
}

// ======== scan step 2: exclusive scan of block sums ========
__global__ void __launch_bounds__(SCAN_BLK) scanb_kernel(
    int* __restrict__ bsum, int* __restrict__ off) {
  __shared__ int s[SCAN_BLK];
  int t = threadIdx.x;
  int v = (t < NSCAN) ? bsum[t] : 0;
  s[t] = v;
  __syncthreads();
  for (int d = 1; d < SCAN_BLK; d <<= 1) {
    int x = (t >= d) ? s[t - d] : 0;
    __syncthreads();
    s[t] += x;
    __syncthreads();
  }
  if (t < NSCAN) bsum[t] = s[t] - v;
  if (t == 0) off[NNODES] = NEDGES;
}

// ======== scan step 3: per-element offsets + cursor + dis ========
__global__ void __launch_bounds__(SCAN_BLK) offsets_kernel(
    const int* __restrict__ degi, const int* __restrict__ bsum,
    int* __restrict__ off, int* __restrict__ cursor, float* __restrict__ dis) {
  int b = blockIdx.x, t = threadIdx.x;
  int i = b * SCAN_BLK + t;
  __shared__ int s[SCAN_BLK];
  int v = (i < NNODES) ? degi[i] : 0;
  s[t] = v;
  __syncthreads();
  for (int d = 1; d < SCAN_BLK; d <<= 1) {
    int x = (t >= d) ? s[t - d] : 0;
    __syncthreads();
    s[t] += x;
    __syncthreads();
  }
  if (i < NNODES) {
    int excl = s[t] - v + bsum[b];
    off[i] = excl;
    cursor[i] = excl;
    dis[i] = rsqrtf((float)v + 1.0f);
  }
}

__global__ void fill_kernel(const int* __restrict__ src, const int* __restrict__ dst,
                            const float* __restrict__ dis,
                            int* __restrict__ cursor, int2* __restrict__ epack) {
  int e = blockIdx.x * blockDim.x + threadIdx.x;
  if (e >= NEDGES) return;
  int s = src[e], d = dst[e];
  int p = atomicAdd(&cursor[d], 1);
  int2 v;
  v.x = s;
  v.y = __float_as_int(dis[s] * dis[d]);
  epack[p] = v;
}

// ======== conv via MFMA + LDS repack epilogue ========
__global__ void __launch_bounds__(256) convm_kernel(
    const unsigned short* __restrict__ Abf, const unsigned short* __restrict__ Wp,
    unsigned short* __restrict__ Bbf) {
  __shared__ __align__(16) unsigned short tile[4][16][136];
  int wave = threadIdx.x >> 6;
  int lane = threadIdx.x & 63;
  int base = blockIdx.x * 64 + wave * 16;
  int l15 = lane & 15, hi = lane >> 4;
  int row = base + l15;
  int rowc = row < NNODES ? row : NNODES - 1;
  bf16x8 a[4];
#pragma unroll
  for (int kk = 0; kk < 4; ++kk)
    a[kk] = *(const bf16x8*)(Abf + (size_t)rowc * HID + kk * 32 + hi * 8);
  f32x4 acc[8];
#pragma unroll
  for (int nt = 0; nt < 8; ++nt) acc[nt] = (f32x4)(0.f);
#pragma unroll
  for (int kk = 0; kk < 4; ++kk) {
#pragma unroll
    for (int nt = 0; nt < 8; ++nt) {
      bf16x8 w = *(const bf16x8*)(Wp + (((nt * 4 + kk) * 64 + lane) << 3));
      acc[nt] = __builtin_amdgcn_mfma_f32_16x16x32_bf16(a[kk], w, acc[nt], 0, 0, 0);
    }
  }
#pragma unroll
  for (int nt = 0; nt < 8; ++nt)
#pragma unroll
    for (int r = 0; r < 4; ++r)
      tile[wave][hi * 4 + r][nt * 16 + l15] = f2bf(acc[nt][r]);
  __syncthreads();
  int trow = lane >> 2, tseg = lane & 3;
  int orow = blockIdx.x * 64 + wave * 16 + trow;
  if (orow < NNODES) {
#pragma unroll
    for (int s = 0; s < 4; ++s) {
      u16x8 v = *(const u16x8*)&tile[wave][trow][tseg * 32 + s * 8];
      *(u16x8*)(Bbf + (size_t)orow * HID + tseg * 32 + s * 8) = v;
    }
  }
}

// ======== gather: wave-per-node, 4 slots x 16 threads x 8 bf16 ========
__global__ void __launch_bounds__(256) gather_kernel(
    const int* __restrict__ off, const int2* __restrict__ epack,
    const float* __restrict__ dis, const float* __restrict__ bias,
    const unsigned short* __restrict__ Bbf, unsigned short* __restrict__ Abf) {
  int wid = threadIdx.x >> 6, lane = threadIdx.x & 63;
  int n = blockIdx.x * 4 + wid;
  int slot = lane >> 4, p = lane & 15;
  int lo = off[n], hi = off[n + 1];
  float acc0[8], acc1[8];
#pragma unroll
  for (int i = 0; i < 8; ++i) { acc0[i] = 0.f; acc1[i] = 0.f; }
  int idx = lo + slot;
  for (; idx + 4 < hi; idx += 8) {
    int2 e0 = epack[idx];
    int2 e1 = epack[idx + 4];
    float w0 = __int_as_float(e0.y);
    float w1 = __int_as_float(e1.y);
    u16x8 v0 = *(const u16x8*)(Bbf + (size_t)e0.x * HID + p * 8);
    u16x8 v1 = *(const u16x8*)(Bbf + (size_t)e1.x * HID + p * 8);
#pragma unroll
    for (int i = 0; i < 8; ++i) acc0[i] = fmaf(bf2f(v0[i]), w0, acc0[i]);
#pragma unroll
    for (int i = 0; i < 8; ++i) acc1[i] = fmaf(bf2f(v1[i]), w1, acc1[i]);
  }
  if (idx < hi) {
    int2 e0 = epack[idx];
    float w0 = __int_as_float(e0.y);
    u16x8 v0 = *(const u16x8*)(Bbf + (size_t)e0.x * HID + p * 8);
#pragma unroll
    for (int i = 0; i < 8; ++i) acc0[i] = fmaf(bf2f(v0[i]), w0, acc0[i]);
  }
#pragma unroll
  for (int i = 0; i < 8; ++i) {
    float a = acc0[i] + acc1[i];
    a += __shfl_xor(a, 16);
    a += __shfl_xor(a, 32);
    acc0[i] = a;
  }
  if (slot == 0) {
    float dn = dis[n];
    float d2 = dn * dn;
    u16x8 selfv = *(const u16x8*)(Bbf + (size_t)n * HID + p * 8);
    float4 b0 = ((const float4*)bias)[p * 2];
    float4 b1 = ((const float4*)bias)[p * 2 + 1];
    float bb[8] = {b0.x, b0.y, b0.z, b0.w, b1.x, b1.y, b1.z, b1.w};
    u16x8 o;
#pragma unroll
    for (int i = 0; i < 8; ++i) {
      float v = fmaxf(fmaf(bf2f(selfv[i]), d2, bb[i]) + acc0[i], 0.f);
      o[i] = f2bf(v);
    }
    *(u16x8*)(Abf + (size_t)n * HID + p * 8) = o;
  }
}

// ======== pool ========
__global__ void __launch_bounds__(128) pool_kernel(
    const unsigned short* __restrict__ Abf, const int* __restrict__ gstart,
    const int* __restrict__ gend, float* __restrict__ sums) {
  int g = blockIdx.x >> 6, c = blockIdx.x & (PCHUNK - 1);
  int j = threadIdx.x;
  int s0 = gstart[g], e0 = gend[g];
  int len = e0 - s0;
  int lo = s0 + (int)((long long)len * c / PCHUNK);
  int hi = s0 + (int)((long long)len * (c + 1) / PCHUNK);
  float acc = 0.f;
  for (int n = lo; n < hi; ++n) acc += bf2f(Abf[(size_t)n * HID + j]);
  if (lo < hi) atomicAdd(&sums[g * HID + j], acc);
}

// ======== classifier head ========
__global__ void __launch_bounds__(64) cls_kernel(
    const float* __restrict__ sums, const int* __restrict__ gstart,
    const int* __restrict__ gend, const float* __restrict__ c1w,
    const float* __restrict__ c1b, const float* __restrict__ c2w,
    const float* __restrict__ c2b, float* __restrict__ out) {
  int g = blockIdx.x;
  int j = threadIdx.x;
  __shared__ float pooled[HID];
  float cnt = (float)(gend[g] - gstart[g]);
  float inv = 1.0f / fmaxf(cnt, 1.0f);
  pooled[j] = sums[g * HID + j] * inv;
  pooled[j + 64] = sums[g * HID + j + 64] * inv;
  __syncthreads();
  float s = c1b[j];
#pragma unroll 8
  for (int k = 0; k < HID; ++k) s = fmaf(pooled[k], c1w[k * 64 + j], s);
  s = fmaxf(s, 0.f) * c2w[j];
#pragma unroll
  for (int off = 32; off; off >>= 1) s += __shfl_down(s, off);
  if (j == 0) out[g] = s + c2b[0];
}

extern "C" void kernel_launch(void* const* d_in, const int* in_sizes, int n_in,
                              void* d_out, int out_size, void* d_ws, size_t ws_size,
                              hipStream_t stream) {
  const float* x = (const float*)d_in[0];
  const int* edge_index = (const int*)d_in[1];
  const int* batch = (const int*)d_in[3];
  const float* enc_w = (const float*)d_in[4];
  const float* enc_b = (const float*)d_in[5];
  const float* ln_g = (const float*)d_in[6];
  const float* ln_b = (const float*)d_in[7];
  const float* conv_ws = (const float*)d_in[10];
  const float* conv_bs = (const float*)d_in[11];
  const float* c1w = (const float*)d_in[12];
  const float* c1b = (const float*)d_in[13];
  const float* c2w = (const float*)d_in[14];
  const float* c2b = (const float*)d_in[15];
  float* out = (float*)d_out;

  unsigned short* Abf = (unsigned short*)d_ws;        // [NNODES*HID] bf16
  unsigned short* Bbf = Abf + (size_t)NNODES * HID;   // [NNODES*HID] bf16
  unsigned short* Wp = Bbf + (size_t)NNODES * HID;    // [3*16384] bf16
  int2* epack = (int2*)(Wp + 3 * 16384);              // [NEDGES]
  int* degi = (int*)(epack + NEDGES);                 // [NNODES]      --+ zeroed
  float* sums = (float*)(degi + NNODES);              // [NGRAPHS*HID] --+ together
  int* off = (int*)(sums + NGRAPHS * HID);            // [NNODES+1]
  int* cursor = off + NNODES + 1;                     // [NNODES]
  float* dis = (float*)(cursor + NNODES);             // [NNODES]
  int* bsum = (int*)(dis + NNODES);                   // [SCAN_BLK]
  int* gstart = bsum + SCAN_BLK;                      // [NGRAPHS]
  int* gend = gstart + NGRAPHS;                       // [NGRAPHS]

  const int* srcp = edge_index;
  const int* dstp = edge_index + NEDGES;

  hipMemsetAsync(degi, 0, (NNODES + NGRAPHS * HID) * sizeof(int), stream);

  prep_kernel<<<ENC_BLKS + CNT_BLKS + BND_BLKS + PKW_BLKS, 256, 0, stream>>>(
      x, enc_w, enc_b, ln_g, ln_b, Abf, dstp, degi, batch, gstart, gend,
      conv_ws, Wp);
  blocksum_kernel<<<NSCAN, SCAN_BLK, 0, stream>>>(degi, bsum);
  scanb_kernel<<<1, SCAN_BLK, 0, stream>>>(bsum, off);
  offsets_kernel<<<NSCAN, SCAN_BLK, 0, stream>>>(degi, bsum, off, cursor, dis);
  fill_kernel<<<(NEDGES + 255) / 256, 256, 0, stream>>>(srcp, dstp, dis, cursor, epack);

  for (int L = 0; L < 3; ++L) {
    convm_kernel<<<(NNODES + 63) / 64, 256, 0, stream>>>(Abf, Wp + (size_t)L * 16384, Bbf);
    gather_kernel<<<NNODES / 4, 256, 0, stream>>>(
        off, epack, dis, conv_bs + (size_t)L * HID, Bbf, Abf);
  }

  pool_kernel<<<NGRAPHS * PCHUNK, 128, 0, stream>>>(Abf, gstart, gend, sums);
  cls_kernel<<<NGRAPHS, 64, 0, stream>>>(sums, gstart, gend, c1w, c1b, c2w, c2b, out);
}

// Round 7
// 225.409 us; speedup vs baseline: 6.8681x; 1.0555x over previous
//
#include <hip/hip_runtime.h>

#define HID 128
#define DNODE 64
#define NNODES 50000
#define NEDGES 600000
#define NGRAPHS 64
#define LN_EPS 1e-5f
#define SCAN_BLK 256
#define NSCAN ((NNODES + SCAN_BLK - 1) / SCAN_BLK)   // 196
#define PCHUNK 64

#define CNT_BLKS ((NEDGES + 255) / 256)   // 2344
#define BND_BLKS ((NNODES + 255) / 256)   // 196
#define PKWC_BLKS (3 * 16384 / 256)       // 192
#define PKWE_BLKS (8192 / 256)            // 32

#define FILL_BLKS ((NEDGES + 255) / 256)  // 2344
#define ENC_BLKS ((NNODES + 63) / 64)     // 782

typedef __attribute__((ext_vector_type(8))) short bf16x8;
typedef __attribute__((ext_vector_type(8))) unsigned short u16x8;
typedef __attribute__((ext_vector_type(4))) float f32x4;

static __device__ __forceinline__ unsigned short f2bf(float f) {
  unsigned int u = __float_as_uint(f);
  u += 0x7fffu + ((u >> 16) & 1u);   // RNE
  return (unsigned short)(u >> 16);
}
static __device__ __forceinline__ float bf2f(unsigned short h) {
  return __uint_as_float(((unsigned int)h) << 16);
}

// ======== prep1: edge-count | graph-bounds | pack conv W | pack enc W ======
__global__ void __launch_bounds__(256) prep1_kernel(
    const int* __restrict__ dst, int* __restrict__ degi,
    const int* __restrict__ batch, int* __restrict__ gstart,
    int* __restrict__ gend, const float* __restrict__ W,
    unsigned short* __restrict__ Wp, const float* __restrict__ enc_w,
    unsigned short* __restrict__ Wpe) {
  int b = blockIdx.x;
  if (b < CNT_BLKS) {
    int e = b * 256 + threadIdx.x;
    if (e < NEDGES) atomicAdd(&degi[dst[e]], 1);
  } else if (b < CNT_BLKS + BND_BLKS) {
    int i = (b - CNT_BLKS) * 256 + threadIdx.x;
    if (i < NNODES) {
      int g = batch[i];
      if (i == 0 || batch[i - 1] != g) gstart[g] = i;
      if (i == NNODES - 1 || batch[i + 1] != g) gend[g] = i + 1;
    }
  } else if (b < CNT_BLKS + BND_BLKS + PKWC_BLKS) {
    int t = (b - CNT_BLKS - BND_BLKS) * 256 + threadIdx.x;
    // Wp[layer][((nt*4+kk)*64+lane)*8+i] = W[layer][kk*32+(lane>>4)*8+i][nt*16+(lane&15)]
    int i = t & 7;
    int lane = (t >> 3) & 63;
    int kk = (t >> 9) & 3;
    int nt = (t >> 11) & 7;
    int layer = t >> 14;
    int k = kk * 32 + (lane >> 4) * 8 + i;
    int n = nt * 16 + (lane & 15);
    Wp[t] = f2bf(W[((size_t)layer * HID + k) * HID + n]);
  } else {
    int t = (b - CNT_BLKS - BND_BLKS - PKWC_BLKS) * 256 + threadIdx.x;
    // Wpe[((nt*2+kk)*64+lane)*8+i] = enc_w[kk*32+(lane>>4)*8+i][nt*16+(lane&15)]
    int i = t & 7;
    int lane = (t >> 3) & 63;
    int kk = (t >> 9) & 1;
    int nt = (t >> 10) & 7;
    int k = kk * 32 + (lane >> 4) * 8 + i;
    int n = nt * 16 + (lane & 15);
    Wpe[t] = f2bf(enc_w[(size_t)k * HID + n]);
  }
}

// ======== scan step 1: per-block degree sums ========
__global__ void __launch_bounds__(SCAN_BLK) blocksum_kernel(
    const int* __restrict__ degi, int* __restrict__ bsum) {
  int i = blockIdx.x * SCAN_BLK + threadIdx.x;
  int v = (i < NNODES) ? degi[i] : 0;
#pragma unroll
  for (int off = 32; off; off >>= 1) v += __shfl_down(v, off);
  __shared__ int wsum[4];
  if ((threadIdx.x & 63) == 0) wsum[threadIdx.x >> 6] = v;
  __syncthreads();
  if (threadIdx.x == 0) bsum[blockIdx.x] = wsum[0] + wsum[1] + wsum[2] + wsum[3];
}

// ======== scan step 2 (merged): inline scan of bsums + per-element offsets ==
__global__ void __launch_bounds__(SCAN_BLK) offsets_kernel(
    const int* __restrict__ degi, const int* __restrict__ bsum,
    int* __restrict__ off, int* __restrict__ cursor, float* __restrict__ dis) {
  int b = blockIdx.x, t = threadIdx.x;
  __shared__ int sb[SCAN_BLK];
  __shared__ int s[SCAN_BLK];
  __shared__ int wred[4];
  sb[t] = (t < NSCAN) ? bsum[t] : 0;
  __syncthreads();
  int v = (t < b) ? sb[t] : 0;
#pragma unroll
  for (int o = 32; o; o >>= 1) v += __shfl_down(v, o);
  if ((t & 63) == 0) wred[t >> 6] = v;
  __syncthreads();
  int base = wred[0] + wred[1] + wred[2] + wred[3];
  int i = b * SCAN_BLK + t;
  int dv = (i < NNODES) ? degi[i] : 0;
  s[t] = dv;
  __syncthreads();
  for (int d = 1; d < SCAN_BLK; d <<= 1) {
    int x = (t >= d) ? s[t - d] : 0;
    __syncthreads();
    s[t] += x;
    __syncthreads();
  }
  if (i < NNODES) {
    int excl = s[t] - dv + base;
    off[i] = excl;
    cursor[i] = excl;
    dis[i] = rsqrtf((float)dv + 1.0f);
  }
  if (b == 0 && t == 0) off[NNODES] = NEDGES;
}

// ======== fused: CSR fill | MFMA encoder (block-range split) ========
__global__ void __launch_bounds__(256) fillenc_kernel(
    const int* __restrict__ src, const int* __restrict__ dst,
    const float* __restrict__ dis, int* __restrict__ cursor,
    int2* __restrict__ epack, const float* __restrict__ x,
    const unsigned short* __restrict__ Wpe, const float* __restrict__ enc_b,
    const float* __restrict__ ln_g, const float* __restrict__ ln_b,
    unsigned short* __restrict__ Abf) {
  __shared__ __align__(16) unsigned short tile[4][16][136];
  int blk = blockIdx.x;
  if (blk < FILL_BLKS) {
    int e = blk * 256 + threadIdx.x;
    if (e >= NEDGES) return;
    int sN = src[e], d = dst[e];
    int p = atomicAdd(&cursor[d], 1);
    int2 v;
    v.x = sN;
    v.y = __float_as_int(dis[sN] * dis[d]);
    epack[p] = v;
    return;
  }
  int b2 = blk - FILL_BLKS;
  int wave = threadIdx.x >> 6;
  int lane = threadIdx.x & 63;
  int l15 = lane & 15, h = lane >> 4;
  int base = b2 * 64 + wave * 16;
  int row = base + l15;
  int rowc = row < NNODES ? row : NNODES - 1;
  // A fragments straight from global x (fp32 -> bf16 in regs)
  const float* xr = x + (size_t)rowc * DNODE;
  bf16x8 a[2];
#pragma unroll
  for (int kk = 0; kk < 2; ++kk) {
    float4 p0 = *(const float4*)(xr + kk * 32 + h * 8);
    float4 p1 = *(const float4*)(xr + kk * 32 + h * 8 + 4);
    a[kk][0] = (short)f2bf(p0.x); a[kk][1] = (short)f2bf(p0.y);
    a[kk][2] = (short)f2bf(p0.z); a[kk][3] = (short)f2bf(p0.w);
    a[kk][4] = (short)f2bf(p1.x); a[kk][5] = (short)f2bf(p1.y);
    a[kk][6] = (short)f2bf(p1.z); a[kk][7] = (short)f2bf(p1.w);
  }
  f32x4 acc[8];
#pragma unroll
  for (int nt = 0; nt < 8; ++nt) acc[nt] = (f32x4)(0.f);
  const bf16x8* wp = (const bf16x8*)Wpe;
#pragma unroll
  for (int kk = 0; kk < 2; ++kk)
#pragma unroll
    for (int nt = 0; nt < 8; ++nt)
      acc[nt] = __builtin_amdgcn_mfma_f32_16x16x32_bf16(a[kk], wp[(nt * 2 + kk) * 64 + lane],
                                                        acc[nt], 0, 0, 0);
  // bias + ReLU + per-row LayerNorm (rows live in 16-lane col groups)
  float s[4] = {0.f, 0.f, 0.f, 0.f}, s2[4] = {0.f, 0.f, 0.f, 0.f};
#pragma unroll
  for (int nt = 0; nt < 8; ++nt) {
    float bcol = enc_b[nt * 16 + l15];
#pragma unroll
    for (int r = 0; r < 4; ++r) {
      float v = fmaxf(acc[nt][r] + bcol, 0.f);
      acc[nt][r] = v;
      s[r] += v;
      s2[r] = fmaf(v, v, s2[r]);
    }
  }
#pragma unroll
  for (int r = 0; r < 4; ++r) {
#pragma unroll
    for (int o = 1; o < 16; o <<= 1) {
      s[r] += __shfl_xor(s[r], o);
      s2[r] += __shfl_xor(s2[r], o);
    }
  }
  float mu[4], rstd[4];
#pragma unroll
  for (int r = 0; r < 4; ++r) {
    mu[r] = s[r] * (1.0f / HID);
    float var = s2[r] * (1.0f / HID) - mu[r] * mu[r];
    rstd[r] = rsqrtf(var + LN_EPS);
  }
#pragma unroll
  for (int nt = 0; nt < 8; ++nt) {
    float gcol = ln_g[nt * 16 + l15], bbcol = ln_b[nt * 16 + l15];
#pragma unroll
    for (int r = 0; r < 4; ++r)
      tile[wave][h * 4 + r][nt * 16 + l15] =
          f2bf((acc[nt][r] - mu[r]) * rstd[r] * gcol + bbcol);
  }
  __syncthreads();
  int trow = lane >> 2, tseg = lane & 3;
  int orow = base + trow;
  if (orow < NNODES) {
#pragma unroll
    for (int q = 0; q < 4; ++q) {
      u16x8 v = *(const u16x8*)&tile[wave][trow][tseg * 32 + q * 8];
      *(u16x8*)(Abf + (size_t)orow * HID + tseg * 32 + q * 8) = v;
    }
  }
}

// ======== conv via MFMA + LDS repack epilogue ========
__global__ void __launch_bounds__(256) convm_kernel(
    const unsigned short* __restrict__ Abf, const unsigned short* __restrict__ Wp,
    unsigned short* __restrict__ Bbf) {
  __shared__ __align__(16) unsigned short tile[4][16][136];
  int wave = threadIdx.x >> 6;
  int lane = threadIdx.x & 63;
  int base = blockIdx.x * 64 + wave * 16;
  int l15 = lane & 15, hi = lane >> 4;
  int row = base + l15;
  int rowc = row < NNODES ? row : NNODES - 1;
  bf16x8 a[4];
#pragma unroll
  for (int kk = 0; kk < 4; ++kk)
    a[kk] = *(const bf16x8*)(Abf + (size_t)rowc * HID + kk * 32 + hi * 8);
  f32x4 acc[8];
#pragma unroll
  for (int nt = 0; nt < 8; ++nt) acc[nt] = (f32x4)(0.f);
#pragma unroll
  for (int kk = 0; kk < 4; ++kk) {
#pragma unroll
    for (int nt = 0; nt < 8; ++nt) {
      bf16x8 w = *(const bf16x8*)(Wp + (((nt * 4 + kk) * 64 + lane) << 3));
      acc[nt] = __builtin_amdgcn_mfma_f32_16x16x32_bf16(a[kk], w, acc[nt], 0, 0, 0);
    }
  }
#pragma unroll
  for (int nt = 0; nt < 8; ++nt)
#pragma unroll
    for (int r = 0; r < 4; ++r)
      tile[wave][hi * 4 + r][nt * 16 + l15] = f2bf(acc[nt][r]);
  __syncthreads();
  int trow = lane >> 2, tseg = lane & 3;
  int orow = blockIdx.x * 64 + wave * 16 + trow;
  if (orow < NNODES) {
#pragma unroll
    for (int s = 0; s < 4; ++s) {
      u16x8 v = *(const u16x8*)&tile[wave][trow][tseg * 32 + s * 8];
      *(u16x8*)(Bbf + (size_t)orow * HID + tseg * 32 + s * 8) = v;
    }
  }
}

// ======== gather: wave-per-node, 4 slots x 16 threads x 8 bf16 ========
__global__ void __launch_bounds__(256) gather_kernel(
    const int* __restrict__ off, const int2* __restrict__ epack,
    const float* __restrict__ dis, const float* __restrict__ bias,
    const unsigned short* __restrict__ Bbf, unsigned short* __restrict__ Abf) {
  int wid = threadIdx.x >> 6, lane = threadIdx.x & 63;
  int n = blockIdx.x * 4 + wid;
  int slot = lane >> 4, p = lane & 15;
  int lo = off[n], hi = off[n + 1];
  float acc0[8], acc1[8];
#pragma unroll
  for (int i = 0; i < 8; ++i) { acc0[i] = 0.f; acc1[i] = 0.f; }
  int idx = lo + slot;
  for (; idx + 4 < hi; idx += 8) {
    int2 e0 = epack[idx];
    int2 e1 = epack[idx + 4];
    float w0 = __int_as_float(e0.y);
    float w1 = __int_as_float(e1.y);
    u16x8 v0 = *(const u16x8*)(Bbf + (size_t)e0.x * HID + p * 8);
    u16x8 v1 = *(const u16x8*)(Bbf + (size_t)e1.x * HID + p * 8);
#pragma unroll
    for (int i = 0; i < 8; ++i) acc0[i] = fmaf(bf2f(v0[i]), w0, acc0[i]);
#pragma unroll
    for (int i = 0; i < 8; ++i) acc1[i] = fmaf(bf2f(v1[i]), w1, acc1[i]);
  }
  if (idx < hi) {
    int2 e0 = epack[idx];
    float w0 = __int_as_float(e0.y);
    u16x8 v0 = *(const u16x8*)(Bbf + (size_t)e0.x * HID + p * 8);
#pragma unroll
    for (int i = 0; i < 8; ++i) acc0[i] = fmaf(bf2f(v0[i]), w0, acc0[i]);
  }
#pragma unroll
  for (int i = 0; i < 8; ++i) {
    float a = acc0[i] + acc1[i];
    a += __shfl_xor(a, 16);
    a += __shfl_xor(a, 32);
    acc0[i] = a;
  }
  if (slot == 0) {
    float dn = dis[n];
    float d2 = dn * dn;
    u16x8 selfv = *(const u16x8*)(Bbf + (size_t)n * HID + p * 8);
    float4 b0 = ((const float4*)bias)[p * 2];
    float4 b1 = ((const float4*)bias)[p * 2 + 1];
    float bb[8] = {b0.x, b0.y, b0.z, b0.w, b1.x, b1.y, b1.z, b1.w};
    u16x8 o;
#pragma unroll
    for (int i = 0; i < 8; ++i) {
      float v = fmaxf(fmaf(bf2f(selfv[i]), d2, bb[i]) + acc0[i], 0.f);
      o[i] = f2bf(v);
    }
    *(u16x8*)(Abf + (size_t)n * HID + p * 8) = o;
  }
}

// ======== pool ========
__global__ void __launch_bounds__(128) pool_kernel(
    const unsigned short* __restrict__ Abf, const int* __restrict__ gstart,
    const int* __restrict__ gend, float* __restrict__ sums) {
  int g = blockIdx.x >> 6, c = blockIdx.x & (PCHUNK - 1);
  int j = threadIdx.x;
  int s0 = gstart[g], e0 = gend[g];
  int len = e0 - s0;
  int lo = s0 + (int)((long long)len * c / PCHUNK);
  int hi = s0 + (int)((long long)len * (c + 1) / PCHUNK);
  float acc = 0.f;
  for (int n = lo; n < hi; ++n) acc += bf2f(Abf[(size_t)n * HID + j]);
  if (lo < hi) atomicAdd(&sums[g * HID + j], acc);
}

// ======== classifier head ========
__global__ void __launch_bounds__(64) cls_kernel(
    const float* __restrict__ sums, const int* __restrict__ gstart,
    const int* __restrict__ gend, const float* __restrict__ c1w,
    const float* __restrict__ c1b, const float* __restrict__ c2w,
    const float* __restrict__ c2b, float* __restrict__ out) {
  int g = blockIdx.x;
  int j = threadIdx.x;
  __shared__ float pooled[HID];
  float cnt = (float)(gend[g] - gstart[g]);
  float inv = 1.0f / fmaxf(cnt, 1.0f);
  pooled[j] = sums[g * HID + j] * inv;
  pooled[j + 64] = sums[g * HID + j + 64] * inv;
  __syncthreads();
  float s = c1b[j];
#pragma unroll 8
  for (int k = 0; k < HID; ++k) s = fmaf(pooled[k], c1w[k * 64 + j], s);
  s = fmaxf(s, 0.f) * c2w[j];
#pragma unroll
  for (int off = 32; off; off >>= 1) s += __shfl_down(s, off);
  if (j == 0) out[g] = s + c2b[0];
}

extern "C" void kernel_launch(void* const* d_in, const int* in_sizes, int n_in,
                              void* d_out, int out_size, void* d_ws, size_t ws_size,
                              hipStream_t stream) {
  const float* x = (const float*)d_in[0];
  const int* edge_index = (const int*)d_in[1];
  const int* batch = (const int*)d_in[3];
  const float* enc_w = (const float*)d_in[4];
  const float* enc_b = (const float*)d_in[5];
  const float* ln_g = (const float*)d_in[6];
  const float* ln_b = (const float*)d_in[7];
  const float* conv_ws = (const float*)d_in[10];
  const float* conv_bs = (const float*)d_in[11];
  const float* c1w = (const float*)d_in[12];
  const float* c1b = (const float*)d_in[13];
  const float* c2w = (const float*)d_in[14];
  const float* c2b = (const float*)d_in[15];
  float* out = (float*)d_out;

  unsigned short* Abf = (unsigned short*)d_ws;        // [NNODES*HID] bf16
  unsigned short* Bbf = Abf + (size_t)NNODES * HID;   // [NNODES*HID] bf16
  unsigned short* Wp = Bbf + (size_t)NNODES * HID;    // [3*16384] bf16
  unsigned short* Wpe = Wp + 3 * 16384;               // [8192] bf16
  int2* epack = (int2*)(Wpe + 8192);                  // [NEDGES]
  int* degi = (int*)(epack + NEDGES);                 // [NNODES]      --+ zeroed
  float* sums = (float*)(degi + NNODES);              // [NGRAPHS*HID] --+ together
  int* off = (int*)(sums + NGRAPHS * HID);            // [NNODES+1]
  int* cursor = off + NNODES + 1;                     // [NNODES]
  float* dis = (float*)(cursor + NNODES);             // [NNODES]
  int* bsum = (int*)(dis + NNODES);                   // [SCAN_BLK]
  int* gstart = bsum + SCAN_BLK;                      // [NGRAPHS]
  int* gend = gstart + NGRAPHS;                       // [NGRAPHS]

  const int* srcp = edge_index;
  const int* dstp = edge_index + NEDGES;

  hipMemsetAsync(degi, 0, (NNODES + NGRAPHS * HID) * sizeof(int), stream);

  prep1_kernel<<<CNT_BLKS + BND_BLKS + PKWC_BLKS + PKWE_BLKS, 256, 0, stream>>>(
      dstp, degi, batch, gstart, gend, conv_ws, Wp, enc_w, Wpe);
  blocksum_kernel<<<NSCAN, SCAN_BLK, 0, stream>>>(degi, bsum);
  offsets_kernel<<<NSCAN, SCAN_BLK, 0, stream>>>(degi, bsum, off, cursor, dis);
  fillenc_kernel<<<FILL_BLKS + ENC_BLKS, 256, 0, stream>>>(
      srcp, dstp, dis, cursor, epack, x, Wpe, enc_b, ln_g, ln_b, Abf);

  for (int L = 0; L < 3; ++L) {
    convm_kernel<<<(NNODES + 63) / 64, 256, 0, stream>>>(Abf, Wp + (size_t)L * 16384, Bbf);
    gather_kernel<<<NNODES / 4, 256, 0, stream>>>(
        off, epack, dis, conv_bs + (size_t)L * HID, Bbf, Abf);
  }

  pool_kernel<<<NGRAPHS * PCHUNK, 128, 0, stream>>>(Abf, gstart, gend, sums);
  cls_kernel<<<NGRAPHS, 64, 0, stream>>>(sums, gstart, gend, c1w, c1b, c2w, c2b, out);
}

// Round 8
// 206.554 us; speedup vs baseline: 7.4950x; 1.0913x over previous
//
#include <hip/hip_runtime.h>

#define HID 128
#define DNODE 64
#define NNODES 50000
#define NEDGES 600000
#define NGRAPHS 64
#define LN_EPS 1e-5f
#define SCAN_BLK 256
#define NSCAN ((NNODES + SCAN_BLK - 1) / SCAN_BLK)   // 196
#define PCHUNK 64

#define CNT_BLKS ((NEDGES + 255) / 256)   // 2344
#define BND_BLKS ((NNODES + 255) / 256)   // 196
#define PKWC_BLKS (3 * 16384 / 256)       // 192
#define PKWE_BLKS (8192 / 256)            // 32

#define ENC_BLKS ((NNODES + 63) / 64)     // 782
#define FILL_BLKS ((NEDGES + 255) / 256)  // 2344

typedef __attribute__((ext_vector_type(8))) short bf16x8;
typedef __attribute__((ext_vector_type(8))) unsigned short u16x8;
typedef __attribute__((ext_vector_type(4))) float f32x4;

static __device__ __forceinline__ unsigned short f2bf(float f) {
  unsigned int u = __float_as_uint(f);
  u += 0x7fffu + ((u >> 16) & 1u);   // RNE
  return (unsigned short)(u >> 16);
}
static __device__ __forceinline__ float bf2f(unsigned short h) {
  return __uint_as_float(((unsigned int)h) << 16);
}

// ======== prep1: edge-count+rank | graph-bounds | pack conv W | pack enc W ==
__global__ void __launch_bounds__(256) prep1_kernel(
    const int* __restrict__ dst, int* __restrict__ degi, int* __restrict__ erank,
    const int* __restrict__ batch, int* __restrict__ gstart,
    int* __restrict__ gend, const float* __restrict__ W,
    unsigned short* __restrict__ Wp, const float* __restrict__ enc_w,
    unsigned short* __restrict__ Wpe) {
  int b = blockIdx.x;
  if (b < CNT_BLKS) {
    int e = b * 256 + threadIdx.x;
    if (e < NEDGES) erank[e] = atomicAdd(&degi[dst[e]], 1);
  } else if (b < CNT_BLKS + BND_BLKS) {
    int i = (b - CNT_BLKS) * 256 + threadIdx.x;
    if (i < NNODES) {
      int g = batch[i];
      if (i == 0 || batch[i - 1] != g) gstart[g] = i;
      if (i == NNODES - 1 || batch[i + 1] != g) gend[g] = i + 1;
    }
  } else if (b < CNT_BLKS + BND_BLKS + PKWC_BLKS) {
    int t = (b - CNT_BLKS - BND_BLKS) * 256 + threadIdx.x;
    // Wp[layer][((nt*4+kk)*64+lane)*8+i] = W[layer][kk*32+(lane>>4)*8+i][nt*16+(lane&15)]
    int i = t & 7;
    int lane = (t >> 3) & 63;
    int kk = (t >> 9) & 3;
    int nt = (t >> 11) & 7;
    int layer = t >> 14;
    int k = kk * 32 + (lane >> 4) * 8 + i;
    int n = nt * 16 + (lane & 15);
    Wp[t] = f2bf(W[((size_t)layer * HID + k) * HID + n]);
  } else {
    int t = (b - CNT_BLKS - BND_BLKS - PKWC_BLKS) * 256 + threadIdx.x;
    // Wpe[((nt*2+kk)*64+lane)*8+i] = enc_w[kk*32+(lane>>4)*8+i][nt*16+(lane&15)]
    int i = t & 7;
    int lane = (t >> 3) & 63;
    int kk = (t >> 9) & 1;
    int nt = (t >> 10) & 7;
    int k = kk * 32 + (lane >> 4) * 8 + i;
    int n = nt * 16 + (lane & 15);
    Wpe[t] = f2bf(enc_w[(size_t)k * HID + n]);
  }
}

// ======== scan step 1: per-block degree sums ========
__global__ void __launch_bounds__(SCAN_BLK) blocksum_kernel(
    const int* __restrict__ degi, int* __restrict__ bsum) {
  int i = blockIdx.x * SCAN_BLK + threadIdx.x;
  int v = (i < NNODES) ? degi[i] : 0;
#pragma unroll
  for (int off = 32; off; off >>= 1) v += __shfl_down(v, off);
  __shared__ int wsum[4];
  if ((threadIdx.x & 63) == 0) wsum[threadIdx.x >> 6] = v;
  __syncthreads();
  if (threadIdx.x == 0) bsum[blockIdx.x] = wsum[0] + wsum[1] + wsum[2] + wsum[3];
}

// ======== scan step 2 (merged): inline scan of bsums + per-element offsets ==
__global__ void __launch_bounds__(SCAN_BLK) offsets_kernel(
    const int* __restrict__ degi, const int* __restrict__ bsum,
    int* __restrict__ off, float* __restrict__ dis) {
  int b = blockIdx.x, t = threadIdx.x;
  __shared__ int sb[SCAN_BLK];
  __shared__ int s[SCAN_BLK];
  __shared__ int wred[4];
  sb[t] = (t < NSCAN) ? bsum[t] : 0;
  __syncthreads();
  int v = (t < b) ? sb[t] : 0;
#pragma unroll
  for (int o = 32; o; o >>= 1) v += __shfl_down(v, o);
  if ((t & 63) == 0) wred[t >> 6] = v;
  __syncthreads();
  int base = wred[0] + wred[1] + wred[2] + wred[3];
  int i = b * SCAN_BLK + t;
  int dv = (i < NNODES) ? degi[i] : 0;
  s[t] = dv;
  __syncthreads();
  for (int d = 1; d < SCAN_BLK; d <<= 1) {
    int x = (t >= d) ? s[t - d] : 0;
    __syncthreads();
    s[t] += x;
    __syncthreads();
  }
  if (i < NNODES) {
    int excl = s[t] - dv + base;
    off[i] = excl;
    dis[i] = rsqrtf((float)dv + 1.0f);
  }
  if (b == 0 && t == 0) off[NNODES] = NEDGES;
}

// ======== fused: MFMA encoder | atomic-free CSR fill ========
__global__ void __launch_bounds__(256) fillenc_kernel(
    const int* __restrict__ src, const int* __restrict__ dst,
    const int* __restrict__ erank, const int* __restrict__ off,
    const float* __restrict__ dis, int2* __restrict__ epack,
    const float* __restrict__ x, const unsigned short* __restrict__ Wpe,
    const float* __restrict__ enc_b, const float* __restrict__ ln_g,
    const float* __restrict__ ln_b, unsigned short* __restrict__ Abf) {
  __shared__ __align__(16) unsigned short tile[4][16][136];
  int blk = blockIdx.x;
  if (blk >= ENC_BLKS) {
    int e = (blk - ENC_BLKS) * 256 + threadIdx.x;
    if (e >= NEDGES) return;
    int d = dst[e];
    int sN = src[e];
    int r = erank[e];
    int2 v;
    v.x = sN;
    v.y = __float_as_int(dis[sN] * dis[d]);
    epack[off[d] + r] = v;
    return;
  }
  int b2 = blk;
  int wave = threadIdx.x >> 6;
  int lane = threadIdx.x & 63;
  int l15 = lane & 15, h = lane >> 4;
  int base = b2 * 64 + wave * 16;
  int row = base + l15;
  int rowc = row < NNODES ? row : NNODES - 1;
  // A fragments straight from global x (fp32 -> bf16 in regs)
  const float* xr = x + (size_t)rowc * DNODE;
  bf16x8 a[2];
#pragma unroll
  for (int kk = 0; kk < 2; ++kk) {
    float4 p0 = *(const float4*)(xr + kk * 32 + h * 8);
    float4 p1 = *(const float4*)(xr + kk * 32 + h * 8 + 4);
    a[kk][0] = (short)f2bf(p0.x); a[kk][1] = (short)f2bf(p0.y);
    a[kk][2] = (short)f2bf(p0.z); a[kk][3] = (short)f2bf(p0.w);
    a[kk][4] = (short)f2bf(p1.x); a[kk][5] = (short)f2bf(p1.y);
    a[kk][6] = (short)f2bf(p1.z); a[kk][7] = (short)f2bf(p1.w);
  }
  f32x4 acc[8];
#pragma unroll
  for (int nt = 0; nt < 8; ++nt) acc[nt] = (f32x4)(0.f);
  const bf16x8* wp = (const bf16x8*)Wpe;
#pragma unroll
  for (int kk = 0; kk < 2; ++kk)
#pragma unroll
    for (int nt = 0; nt < 8; ++nt)
      acc[nt] = __builtin_amdgcn_mfma_f32_16x16x32_bf16(a[kk], wp[(nt * 2 + kk) * 64 + lane],
                                                        acc[nt], 0, 0, 0);
  // bias + ReLU + per-row LayerNorm (rows live in 16-lane col groups)
  float s[4] = {0.f, 0.f, 0.f, 0.f}, s2[4] = {0.f, 0.f, 0.f, 0.f};
#pragma unroll
  for (int nt = 0; nt < 8; ++nt) {
    float bcol = enc_b[nt * 16 + l15];
#pragma unroll
    for (int r = 0; r < 4; ++r) {
      float v = fmaxf(acc[nt][r] + bcol, 0.f);
      acc[nt][r] = v;
      s[r] += v;
      s2[r] = fmaf(v, v, s2[r]);
    }
  }
#pragma unroll
  for (int r = 0; r < 4; ++r) {
#pragma unroll
    for (int o = 1; o < 16; o <<= 1) {
      s[r] += __shfl_xor(s[r], o);
      s2[r] += __shfl_xor(s2[r], o);
    }
  }
  float mu[4], rstd[4];
#pragma unroll
  for (int r = 0; r < 4; ++r) {
    mu[r] = s[r] * (1.0f / HID);
    float var = s2[r] * (1.0f / HID) - mu[r] * mu[r];
    rstd[r] = rsqrtf(var + LN_EPS);
  }
#pragma unroll
  for (int nt = 0; nt < 8; ++nt) {
    float gcol = ln_g[nt * 16 + l15], bbcol = ln_b[nt * 16 + l15];
#pragma unroll
    for (int r = 0; r < 4; ++r)
      tile[wave][h * 4 + r][nt * 16 + l15] =
          f2bf((acc[nt][r] - mu[r]) * rstd[r] * gcol + bbcol);
  }
  __syncthreads();
  int trow = lane >> 2, tseg = lane & 3;
  int orow = base + trow;
  if (orow < NNODES) {
#pragma unroll
    for (int q = 0; q < 4; ++q) {
      u16x8 v = *(const u16x8*)&tile[wave][trow][tseg * 32 + q * 8];
      *(u16x8*)(Abf + (size_t)orow * HID + tseg * 32 + q * 8) = v;
    }
  }
}

// ======== conv via MFMA + LDS repack epilogue ========
__global__ void __launch_bounds__(256) convm_kernel(
    const unsigned short* __restrict__ Abf, const unsigned short* __restrict__ Wp,
    unsigned short* __restrict__ Bbf) {
  __shared__ __align__(16) unsigned short tile[4][16][136];
  int wave = threadIdx.x >> 6;
  int lane = threadIdx.x & 63;
  int base = blockIdx.x * 64 + wave * 16;
  int l15 = lane & 15, hi = lane >> 4;
  int row = base + l15;
  int rowc = row < NNODES ? row : NNODES - 1;
  bf16x8 a[4];
#pragma unroll
  for (int kk = 0; kk < 4; ++kk)
    a[kk] = *(const bf16x8*)(Abf + (size_t)rowc * HID + kk * 32 + hi * 8);
  f32x4 acc[8];
#pragma unroll
  for (int nt = 0; nt < 8; ++nt) acc[nt] = (f32x4)(0.f);
#pragma unroll
  for (int kk = 0; kk < 4; ++kk) {
#pragma unroll
    for (int nt = 0; nt < 8; ++nt) {
      bf16x8 w = *(const bf16x8*)(Wp + (((nt * 4 + kk) * 64 + lane) << 3));
      acc[nt] = __builtin_amdgcn_mfma_f32_16x16x32_bf16(a[kk], w, acc[nt], 0, 0, 0);
    }
  }
#pragma unroll
  for (int nt = 0; nt < 8; ++nt)
#pragma unroll
    for (int r = 0; r < 4; ++r)
      tile[wave][hi * 4 + r][nt * 16 + l15] = f2bf(acc[nt][r]);
  __syncthreads();
  int trow = lane >> 2, tseg = lane & 3;
  int orow = blockIdx.x * 64 + wave * 16 + trow;
  if (orow < NNODES) {
#pragma unroll
    for (int s = 0; s < 4; ++s) {
      u16x8 v = *(const u16x8*)&tile[wave][trow][tseg * 32 + s * 8];
      *(u16x8*)(Bbf + (size_t)orow * HID + tseg * 32 + s * 8) = v;
    }
  }
}

// ======== gather: wave-per-node, 4 slots x 16 threads x 8 bf16 ========
__global__ void __launch_bounds__(256) gather_kernel(
    const int* __restrict__ off, const int2* __restrict__ epack,
    const float* __restrict__ dis, const float* __restrict__ bias,
    const unsigned short* __restrict__ Bbf, unsigned short* __restrict__ Abf) {
  int wid = threadIdx.x >> 6, lane = threadIdx.x & 63;
  int n = blockIdx.x * 4 + wid;
  int slot = lane >> 4, p = lane & 15;
  int lo = off[n], hi = off[n + 1];
  float acc0[8], acc1[8];
#pragma unroll
  for (int i = 0; i < 8; ++i) { acc0[i] = 0.f; acc1[i] = 0.f; }
  int idx = lo + slot;
  for (; idx + 4 < hi; idx += 8) {
    int2 e0 = epack[idx];
    int2 e1 = epack[idx + 4];
    float w0 = __int_as_float(e0.y);
    float w1 = __int_as_float(e1.y);
    u16x8 v0 = *(const u16x8*)(Bbf + (size_t)e0.x * HID + p * 8);
    u16x8 v1 = *(const u16x8*)(Bbf + (size_t)e1.x * HID + p * 8);
#pragma unroll
    for (int i = 0; i < 8; ++i) acc0[i] = fmaf(bf2f(v0[i]), w0, acc0[i]);
#pragma unroll
    for (int i = 0; i < 8; ++i) acc1[i] = fmaf(bf2f(v1[i]), w1, acc1[i]);
  }
  if (idx < hi) {
    int2 e0 = epack[idx];
    float w0 = __int_as_float(e0.y);
    u16x8 v0 = *(const u16x8*)(Bbf + (size_t)e0.x * HID + p * 8);
#pragma unroll
    for (int i = 0; i < 8; ++i) acc0[i] = fmaf(bf2f(v0[i]), w0, acc0[i]);
  }
#pragma unroll
  for (int i = 0; i < 8; ++i) {
    float a = acc0[i] + acc1[i];
    a += __shfl_xor(a, 16);
    a += __shfl_xor(a, 32);
    acc0[i] = a;
  }
  if (slot == 0) {
    float dn = dis[n];
    float d2 = dn * dn;
    u16x8 selfv = *(const u16x8*)(Bbf + (size_t)n * HID + p * 8);
    float4 b0 = ((const float4*)bias)[p * 2];
    float4 b1 = ((const float4*)bias)[p * 2 + 1];
    float bb[8] = {b0.x, b0.y, b0.z, b0.w, b1.x, b1.y, b1.z, b1.w};
    u16x8 o;
#pragma unroll
    for (int i = 0; i < 8; ++i) {
      float v = fmaxf(fmaf(bf2f(selfv[i]), d2, bb[i]) + acc0[i], 0.f);
      o[i] = f2bf(v);
    }
    *(u16x8*)(Abf + (size_t)n * HID + p * 8) = o;
  }
}

// ======== pool ========
__global__ void __launch_bounds__(128) pool_kernel(
    const unsigned short* __restrict__ Abf, const int* __restrict__ gstart,
    const int* __restrict__ gend, float* __restrict__ sums) {
  int g = blockIdx.x >> 6, c = blockIdx.x & (PCHUNK - 1);
  int j = threadIdx.x;
  int s0 = gstart[g], e0 = gend[g];
  int len = e0 - s0;
  int lo = s0 + (int)((long long)len * c / PCHUNK);
  int hi = s0 + (int)((long long)len * (c + 1) / PCHUNK);
  float acc = 0.f;
  for (int n = lo; n < hi; ++n) acc += bf2f(Abf[(size_t)n * HID + j]);
  if (lo < hi) atomicAdd(&sums[g * HID + j], acc);
}

// ======== classifier head ========
__global__ void __launch_bounds__(64) cls_kernel(
    const float* __restrict__ sums, const int* __restrict__ gstart,
    const int* __restrict__ gend, const float* __restrict__ c1w,
    const float* __restrict__ c1b, const float* __restrict__ c2w,
    const float* __restrict__ c2b, float* __restrict__ out) {
  int g = blockIdx.x;
  int j = threadIdx.x;
  __shared__ float pooled[HID];
  float cnt = (float)(gend[g] - gstart[g]);
  float inv = 1.0f / fmaxf(cnt, 1.0f);
  pooled[j] = sums[g * HID + j] * inv;
  pooled[j + 64] = sums[g * HID + j + 64] * inv;
  __syncthreads();
  float s = c1b[j];
#pragma unroll 8
  for (int k = 0; k < HID; ++k) s = fmaf(pooled[k], c1w[k * 64 + j], s);
  s = fmaxf(s, 0.f) * c2w[j];
#pragma unroll
  for (int off = 32; off; off >>= 1) s += __shfl_down(s, off);
  if (j == 0) out[g] = s + c2b[0];
}

extern "C" void kernel_launch(void* const* d_in, const int* in_sizes, int n_in,
                              void* d_out, int out_size, void* d_ws, size_t ws_size,
                              hipStream_t stream) {
  const float* x = (const float*)d_in[0];
  const int* edge_index = (const int*)d_in[1];
  const int* batch = (const int*)d_in[3];
  const float* enc_w = (const float*)d_in[4];
  const float* enc_b = (const float*)d_in[5];
  const float* ln_g = (const float*)d_in[6];
  const float* ln_b = (const float*)d_in[7];
  const float* conv_ws = (const float*)d_in[10];
  const float* conv_bs = (const float*)d_in[11];
  const float* c1w = (const float*)d_in[12];
  const float* c1b = (const float*)d_in[13];
  const float* c2w = (const float*)d_in[14];
  const float* c2b = (const float*)d_in[15];
  float* out = (float*)d_out;

  unsigned short* Abf = (unsigned short*)d_ws;        // [NNODES*HID] bf16
  unsigned short* Bbf = Abf + (size_t)NNODES * HID;   // [NNODES*HID] bf16
  unsigned short* Wp = Bbf + (size_t)NNODES * HID;    // [3*16384] bf16
  unsigned short* Wpe = Wp + 3 * 16384;               // [8192] bf16
  int2* epack = (int2*)(Wpe + 8192);                  // [NEDGES]
  int* erank = (int*)(epack + NEDGES);                // [NEDGES]
  int* degi = erank + NEDGES;                         // [NNODES]      --+ zeroed
  float* sums = (float*)(degi + NNODES);              // [NGRAPHS*HID] --+ together
  int* off = (int*)(sums + NGRAPHS * HID);            // [NNODES+1]
  float* dis = (float*)(off + NNODES + 1);            // [NNODES]
  int* bsum = (int*)(dis + NNODES);                   // [SCAN_BLK]
  int* gstart = bsum + SCAN_BLK;                      // [NGRAPHS]
  int* gend = gstart + NGRAPHS;                       // [NGRAPHS]

  const int* srcp = edge_index;
  const int* dstp = edge_index + NEDGES;

  hipMemsetAsync(degi, 0, (NNODES + NGRAPHS * HID) * sizeof(int), stream);

  prep1_kernel<<<CNT_BLKS + BND_BLKS + PKWC_BLKS + PKWE_BLKS, 256, 0, stream>>>(
      dstp, degi, erank, batch, gstart, gend, conv_ws, Wp, enc_w, Wpe);
  blocksum_kernel<<<NSCAN, SCAN_BLK, 0, stream>>>(degi, bsum);
  offsets_kernel<<<NSCAN, SCAN_BLK, 0, stream>>>(degi, bsum, off, dis);
  fillenc_kernel<<<ENC_BLKS + FILL_BLKS, 256, 0, stream>>>(
      srcp, dstp, erank, off, dis, epack, x, Wpe, enc_b, ln_g, ln_b, Abf);

  for (int L = 0; L < 3; ++L) {
    convm_kernel<<<(NNODES + 63) / 64, 256, 0, stream>>>(Abf, Wp + (size_t)L * 16384, Bbf);
    gather_kernel<<<NNODES / 4, 256, 0, stream>>>(
        off, epack, dis, conv_bs + (size_t)L * HID, Bbf, Abf);
  }

  pool_kernel<<<NGRAPHS * PCHUNK, 128, 0, stream>>>(Abf, gstart, gend, sums);
  cls_kernel<<<NGRAPHS, 64, 0, stream>>>(sums, gstart, gend, c1w, c1b, c2w, c2b, out);
}

// Round 9
// 206.421 us; speedup vs baseline: 7.4999x; 1.0006x over previous
//
#include <hip/hip_runtime.h>

#define HID 128
#define DNODE 64
#define NNODES 50000
#define NEDGES 600000
#define NGRAPHS 64
#define LN_EPS 1e-5f
#define SCAN_BLK 256
#define NSCAN ((NNODES + SCAN_BLK - 1) / SCAN_BLK)   // 196
#define PCHUNK 64

#define CNT_BLKS ((NEDGES + 255) / 256)   // 2344
#define BND_BLKS ((NNODES + 255) / 256)   // 196
#define PKWC_BLKS (3 * 16384 / 256)       // 192
#define PKWE_BLKS (8192 / 256)            // 32

#define ENC_BLKS ((NNODES + 63) / 64)     // 782
#define FILL_BLKS ((NEDGES + 255) / 256)  // 2344

#define NZERO (NNODES + NGRAPHS * HID)    // ints to zero (degi+sums) = 58192
#define NZERO4 (NZERO / 4)                // 14548 int4 (exact)

typedef __attribute__((ext_vector_type(8))) short bf16x8;
typedef __attribute__((ext_vector_type(8))) unsigned short u16x8;
typedef __attribute__((ext_vector_type(4))) float f32x4;

static __device__ __forceinline__ unsigned short f2bf(float f) {
  unsigned int u = __float_as_uint(f);
  u += 0x7fffu + ((u >> 16) & 1u);   // RNE
  return (unsigned short)(u >> 16);
}
static __device__ __forceinline__ float bf2f(unsigned short h) {
  return __uint_as_float(((unsigned int)h) << 16);
}

// ======== zero: degi+sums (hipMemsetAsync's fill kernel costs 40us!) ========
__global__ void __launch_bounds__(256) zero_kernel(int4* __restrict__ p) {
  int i = blockIdx.x * 256 + threadIdx.x;
  if (i < NZERO4) p[i] = make_int4(0, 0, 0, 0);
}

// ======== prep1: edge-count+rank | graph-bounds | pack conv W | pack enc W ==
__global__ void __launch_bounds__(256) prep1_kernel(
    const int* __restrict__ dst, int* __restrict__ degi, int* __restrict__ erank,
    const int* __restrict__ batch, int* __restrict__ gstart,
    int* __restrict__ gend, const float* __restrict__ W,
    unsigned short* __restrict__ Wp, const float* __restrict__ enc_w,
    unsigned short* __restrict__ Wpe) {
  int b = blockIdx.x;
  if (b < CNT_BLKS) {
    int e = b * 256 + threadIdx.x;
    if (e < NEDGES) erank[e] = atomicAdd(&degi[dst[e]], 1);
  } else if (b < CNT_BLKS + BND_BLKS) {
    int i = (b - CNT_BLKS) * 256 + threadIdx.x;
    if (i < NNODES) {
      int g = batch[i];
      if (i == 0 || batch[i - 1] != g) gstart[g] = i;
      if (i == NNODES - 1 || batch[i + 1] != g) gend[g] = i + 1;
    }
  } else if (b < CNT_BLKS + BND_BLKS + PKWC_BLKS) {
    int t = (b - CNT_BLKS - BND_BLKS) * 256 + threadIdx.x;
    // Wp[layer][((nt*4+kk)*64+lane)*8+i] = W[layer][kk*32+(lane>>4)*8+i][nt*16+(lane&15)]
    int i = t & 7;
    int lane = (t >> 3) & 63;
    int kk = (t >> 9) & 3;
    int nt = (t >> 11) & 7;
    int layer = t >> 14;
    int k = kk * 32 + (lane >> 4) * 8 + i;
    int n = nt * 16 + (lane & 15);
    Wp[t] = f2bf(W[((size_t)layer * HID + k) * HID + n]);
  } else {
    int t = (b - CNT_BLKS - BND_BLKS - PKWC_BLKS) * 256 + threadIdx.x;
    // Wpe[((nt*2+kk)*64+lane)*8+i] = enc_w[kk*32+(lane>>4)*8+i][nt*16+(lane&15)]
    int i = t & 7;
    int lane = (t >> 3) & 63;
    int kk = (t >> 9) & 1;
    int nt = (t >> 10) & 7;
    int k = kk * 32 + (lane >> 4) * 8 + i;
    int n = nt * 16 + (lane & 15);
    Wpe[t] = f2bf(enc_w[(size_t)k * HID + n]);
  }
}

// ======== scan step 1: per-block degree sums ========
__global__ void __launch_bounds__(SCAN_BLK) blocksum_kernel(
    const int* __restrict__ degi, int* __restrict__ bsum) {
  int i = blockIdx.x * SCAN_BLK + threadIdx.x;
  int v = (i < NNODES) ? degi[i] : 0;
#pragma unroll
  for (int off = 32; off; off >>= 1) v += __shfl_down(v, off);
  __shared__ int wsum[4];
  if ((threadIdx.x & 63) == 0) wsum[threadIdx.x >> 6] = v;
  __syncthreads();
  if (threadIdx.x == 0) bsum[blockIdx.x] = wsum[0] + wsum[1] + wsum[2] + wsum[3];
}

// ======== scan step 2 (merged): inline scan of bsums + per-element offsets ==
__global__ void __launch_bounds__(SCAN_BLK) offsets_kernel(
    const int* __restrict__ degi, const int* __restrict__ bsum,
    int* __restrict__ off, float* __restrict__ dis) {
  int b = blockIdx.x, t = threadIdx.x;
  __shared__ int sb[SCAN_BLK];
  __shared__ int s[SCAN_BLK];
  __shared__ int wred[4];
  sb[t] = (t < NSCAN) ? bsum[t] : 0;
  __syncthreads();
  int v = (t < b) ? sb[t] : 0;
#pragma unroll
  for (int o = 32; o; o >>= 1) v += __shfl_down(v, o);
  if ((t & 63) == 0) wred[t >> 6] = v;
  __syncthreads();
  int base = wred[0] + wred[1] + wred[2] + wred[3];
  int i = b * SCAN_BLK + t;
  int dv = (i < NNODES) ? degi[i] : 0;
  s[t] = dv;
  __syncthreads();
  for (int d = 1; d < SCAN_BLK; d <<= 1) {
    int x = (t >= d) ? s[t - d] : 0;
    __syncthreads();
    s[t] += x;
    __syncthreads();
  }
  if (i < NNODES) {
    int excl = s[t] - dv + base;
    off[i] = excl;
    dis[i] = rsqrtf((float)dv + 1.0f);
  }
  if (b == 0 && t == 0) off[NNODES] = NEDGES;
}

// ======== fused: MFMA encoder | atomic-free CSR fill ========
__global__ void __launch_bounds__(256) fillenc_kernel(
    const int* __restrict__ src, const int* __restrict__ dst,
    const int* __restrict__ erank, const int* __restrict__ off,
    const float* __restrict__ dis, int2* __restrict__ epack,
    const float* __restrict__ x, const unsigned short* __restrict__ Wpe,
    const float* __restrict__ enc_b, const float* __restrict__ ln_g,
    const float* __restrict__ ln_b, unsigned short* __restrict__ Abf) {
  __shared__ __align__(16) unsigned short tile[4][16][136];
  int blk = blockIdx.x;
  if (blk >= ENC_BLKS) {
    int e = (blk - ENC_BLKS) * 256 + threadIdx.x;
    if (e >= NEDGES) return;
    int d = dst[e];
    int sN = src[e];
    int r = erank[e];
    int2 v;
    v.x = sN;
    v.y = __float_as_int(dis[sN] * dis[d]);
    epack[off[d] + r] = v;
    return;
  }
  int b2 = blk;
  int wave = threadIdx.x >> 6;
  int lane = threadIdx.x & 63;
  int l15 = lane & 15, h = lane >> 4;
  int base = b2 * 64 + wave * 16;
  int row = base + l15;
  int rowc = row < NNODES ? row : NNODES - 1;
  // A fragments straight from global x (fp32 -> bf16 in regs)
  const float* xr = x + (size_t)rowc * DNODE;
  bf16x8 a[2];
#pragma unroll
  for (int kk = 0; kk < 2; ++kk) {
    float4 p0 = *(const float4*)(xr + kk * 32 + h * 8);
    float4 p1 = *(const float4*)(xr + kk * 32 + h * 8 + 4);
    a[kk][0] = (short)f2bf(p0.x); a[kk][1] = (short)f2bf(p0.y);
    a[kk][2] = (short)f2bf(p0.z); a[kk][3] = (short)f2bf(p0.w);
    a[kk][4] = (short)f2bf(p1.x); a[kk][5] = (short)f2bf(p1.y);
    a[kk][6] = (short)f2bf(p1.z); a[kk][7] = (short)f2bf(p1.w);
  }
  f32x4 acc[8];
#pragma unroll
  for (int nt = 0; nt < 8; ++nt) acc[nt] = (f32x4)(0.f);
  const bf16x8* wp = (const bf16x8*)Wpe;
#pragma unroll
  for (int kk = 0; kk < 2; ++kk)
#pragma unroll
    for (int nt = 0; nt < 8; ++nt)
      acc[nt] = __builtin_amdgcn_mfma_f32_16x16x32_bf16(a[kk], wp[(nt * 2 + kk) * 64 + lane],
                                                        acc[nt], 0, 0, 0);
  // bias + ReLU + per-row LayerNorm (rows live in 16-lane col groups)
  float s[4] = {0.f, 0.f, 0.f, 0.f}, s2[4] = {0.f, 0.f, 0.f, 0.f};
#pragma unroll
  for (int nt = 0; nt < 8; ++nt) {
    float bcol = enc_b[nt * 16 + l15];
#pragma unroll
    for (int r = 0; r < 4; ++r) {
      float v = fmaxf(acc[nt][r] + bcol, 0.f);
      acc[nt][r] = v;
      s[r] += v;
      s2[r] = fmaf(v, v, s2[r]);
    }
  }
#pragma unroll
  for (int r = 0; r < 4; ++r) {
#pragma unroll
    for (int o = 1; o < 16; o <<= 1) {
      s[r] += __shfl_xor(s[r], o);
      s2[r] += __shfl_xor(s2[r], o);
    }
  }
  float mu[4], rstd[4];
#pragma unroll
  for (int r = 0; r < 4; ++r) {
    mu[r] = s[r] * (1.0f / HID);
    float var = s2[r] * (1.0f / HID) - mu[r] * mu[r];
    rstd[r] = rsqrtf(var + LN_EPS);
  }
#pragma unroll
  for (int nt = 0; nt < 8; ++nt) {
    float gcol = ln_g[nt * 16 + l15], bbcol = ln_b[nt * 16 + l15];
#pragma unroll
    for (int r = 0; r < 4; ++r)
      tile[wave][h * 4 + r][nt * 16 + l15] =
          f2bf((acc[nt][r] - mu[r]) * rstd[r] * gcol + bbcol);
  }
  __syncthreads();
  int trow = lane >> 2, tseg = lane & 3;
  int orow = base + trow;
  if (orow < NNODES) {
#pragma unroll
    for (int q = 0; q < 4; ++q) {
      u16x8 v = *(const u16x8*)&tile[wave][trow][tseg * 32 + q * 8];
      *(u16x8*)(Abf + (size_t)orow * HID + tseg * 32 + q * 8) = v;
    }
  }
}

// ======== conv via MFMA + LDS repack epilogue ========
__global__ void __launch_bounds__(256) convm_kernel(
    const unsigned short* __restrict__ Abf, const unsigned short* __restrict__ Wp,
    unsigned short* __restrict__ Bbf) {
  __shared__ __align__(16) unsigned short tile[4][16][136];
  int wave = threadIdx.x >> 6;
  int lane = threadIdx.x & 63;
  int base = blockIdx.x * 64 + wave * 16;
  int l15 = lane & 15, hi = lane >> 4;
  int row = base + l15;
  int rowc = row < NNODES ? row : NNODES - 1;
  bf16x8 a[4];
#pragma unroll
  for (int kk = 0; kk < 4; ++kk)
    a[kk] = *(const bf16x8*)(Abf + (size_t)rowc * HID + kk * 32 + hi * 8);
  f32x4 acc[8];
#pragma unroll
  for (int nt = 0; nt < 8; ++nt) acc[nt] = (f32x4)(0.f);
#pragma unroll
  for (int kk = 0; kk < 4; ++kk) {
#pragma unroll
    for (int nt = 0; nt < 8; ++nt) {
      bf16x8 w = *(const bf16x8*)(Wp + (((nt * 4 + kk) * 64 + lane) << 3));
      acc[nt] = __builtin_amdgcn_mfma_f32_16x16x32_bf16(a[kk], w, acc[nt], 0, 0, 0);
    }
  }
#pragma unroll
  for (int nt = 0; nt < 8; ++nt)
#pragma unroll
    for (int r = 0; r < 4; ++r)
      tile[wave][hi * 4 + r][nt * 16 + l15] = f2bf(acc[nt][r]);
  __syncthreads();
  int trow = lane >> 2, tseg = lane & 3;
  int orow = blockIdx.x * 64 + wave * 16 + trow;
  if (orow < NNODES) {
#pragma unroll
    for (int s = 0; s < 4; ++s) {
      u16x8 v = *(const u16x8*)&tile[wave][trow][tseg * 32 + s * 8];
      *(u16x8*)(Bbf + (size_t)orow * HID + tseg * 32 + s * 8) = v;
    }
  }
}

// ======== gather: wave-per-node, 4 slots x 16 threads x 8 bf16 ========
__global__ void __launch_bounds__(256) gather_kernel(
    const int* __restrict__ off, const int2* __restrict__ epack,
    const float* __restrict__ dis, const float* __restrict__ bias,
    const unsigned short* __restrict__ Bbf, unsigned short* __restrict__ Abf) {
  int wid = threadIdx.x >> 6, lane = threadIdx.x & 63;
  int n = blockIdx.x * 4 + wid;
  int slot = lane >> 4, p = lane & 15;
  int lo = off[n], hi = off[n + 1];
  float acc0[8], acc1[8];
#pragma unroll
  for (int i = 0; i < 8; ++i) { acc0[i] = 0.f; acc1[i] = 0.f; }
  int idx = lo + slot;
  for (; idx + 4 < hi; idx += 8) {
    int2 e0 = epack[idx];
    int2 e1 = epack[idx + 4];
    float w0 = __int_as_float(e0.y);
    float w1 = __int_as_float(e1.y);
    u16x8 v0 = *(const u16x8*)(Bbf + (size_t)e0.x * HID + p * 8);
    u16x8 v1 = *(const u16x8*)(Bbf + (size_t)e1.x * HID + p * 8);
#pragma unroll
    for (int i = 0; i < 8; ++i) acc0[i] = fmaf(bf2f(v0[i]), w0, acc0[i]);
#pragma unroll
    for (int i = 0; i < 8; ++i) acc1[i] = fmaf(bf2f(v1[i]), w1, acc1[i]);
  }
  if (idx < hi) {
    int2 e0 = epack[idx];
    float w0 = __int_as_float(e0.y);
    u16x8 v0 = *(const u16x8*)(Bbf + (size_t)e0.x * HID + p * 8);
#pragma unroll
    for (int i = 0; i < 8; ++i) acc0[i] = fmaf(bf2f(v0[i]), w0, acc0[i]);
  }
#pragma unroll
  for (int i = 0; i < 8; ++i) {
    float a = acc0[i] + acc1[i];
    a += __shfl_xor(a, 16);
    a += __shfl_xor(a, 32);
    acc0[i] = a;
  }
  if (slot == 0) {
    float dn = dis[n];
    float d2 = dn * dn;
    u16x8 selfv = *(const u16x8*)(Bbf + (size_t)n * HID + p * 8);
    float4 b0 = ((const float4*)bias)[p * 2];
    float4 b1 = ((const float4*)bias)[p * 2 + 1];
    float bb[8] = {b0.x, b0.y, b0.z, b0.w, b1.x, b1.y, b1.z, b1.w};
    u16x8 o;
#pragma unroll
    for (int i = 0; i < 8; ++i) {
      float v = fmaxf(fmaf(bf2f(selfv[i]), d2, bb[i]) + acc0[i], 0.f);
      o[i] = f2bf(v);
    }
    *(u16x8*)(Abf + (size_t)n * HID + p * 8) = o;
  }
}

// ======== pool ========
__global__ void __launch_bounds__(128) pool_kernel(
    const unsigned short* __restrict__ Abf, const int* __restrict__ gstart,
    const int* __restrict__ gend, float* __restrict__ sums) {
  int g = blockIdx.x >> 6, c = blockIdx.x & (PCHUNK - 1);
  int j = threadIdx.x;
  int s0 = gstart[g], e0 = gend[g];
  int len = e0 - s0;
  int lo = s0 + (int)((long long)len * c / PCHUNK);
  int hi = s0 + (int)((long long)len * (c + 1) / PCHUNK);
  float acc = 0.f;
  for (int n = lo; n < hi; ++n) acc += bf2f(Abf[(size_t)n * HID + j]);
  if (lo < hi) atomicAdd(&sums[g * HID + j], acc);
}

// ======== classifier head ========
__global__ void __launch_bounds__(64) cls_kernel(
    const float* __restrict__ sums, const int* __restrict__ gstart,
    const int* __restrict__ gend, const float* __restrict__ c1w,
    const float* __restrict__ c1b, const float* __restrict__ c2w,
    const float* __restrict__ c2b, float* __restrict__ out) {
  int g = blockIdx.x;
  int j = threadIdx.x;
  __shared__ float pooled[HID];
  float cnt = (float)(gend[g] - gstart[g]);
  float inv = 1.0f / fmaxf(cnt, 1.0f);
  pooled[j] = sums[g * HID + j] * inv;
  pooled[j + 64] = sums[g * HID + j + 64] * inv;
  __syncthreads();
  float s = c1b[j];
#pragma unroll 8
  for (int k = 0; k < HID; ++k) s = fmaf(pooled[k], c1w[k * 64 + j], s);
  s = fmaxf(s, 0.f) * c2w[j];
#pragma unroll
  for (int off = 32; off; off >>= 1) s += __shfl_down(s, off);
  if (j == 0) out[g] = s + c2b[0];
}

extern "C" void kernel_launch(void* const* d_in, const int* in_sizes, int n_in,
                              void* d_out, int out_size, void* d_ws, size_t ws_size,
                              hipStream_t stream) {
  const float* x = (const float*)d_in[0];
  const int* edge_index = (const int*)d_in[1];
  const int* batch = (const int*)d_in[3];
  const float* enc_w = (const float*)d_in[4];
  const float* enc_b = (const float*)d_in[5];
  const float* ln_g = (const float*)d_in[6];
  const float* ln_b = (const float*)d_in[7];
  const float* conv_ws = (const float*)d_in[10];
  const float* conv_bs = (const float*)d_in[11];
  const float* c1w = (const float*)d_in[12];
  const float* c1b = (const float*)d_in[13];
  const float* c2w = (const float*)d_in[14];
  const float* c2b = (const float*)d_in[15];
  float* out = (float*)d_out;

  unsigned short* Abf = (unsigned short*)d_ws;        // [NNODES*HID] bf16
  unsigned short* Bbf = Abf + (size_t)NNODES * HID;   // [NNODES*HID] bf16
  unsigned short* Wp = Bbf + (size_t)NNODES * HID;    // [3*16384] bf16
  unsigned short* Wpe = Wp + 3 * 16384;               // [8192] bf16
  int2* epack = (int2*)(Wpe + 8192);                  // [NEDGES]
  int* erank = (int*)(epack + NEDGES);                // [NEDGES]
  int* degi = erank + NEDGES;                         // [NNODES]      --+ zeroed
  float* sums = (float*)(degi + NNODES);              // [NGRAPHS*HID] --+ together
  int* off = (int*)(sums + NGRAPHS * HID);            // [NNODES+1]
  float* dis = (float*)(off + NNODES + 1);            // [NNODES]
  int* bsum = (int*)(dis + NNODES);                   // [SCAN_BLK]
  int* gstart = bsum + SCAN_BLK;                      // [NGRAPHS]
  int* gend = gstart + NGRAPHS;                       // [NGRAPHS]

  const int* srcp = edge_index;
  const int* dstp = edge_index + NEDGES;

  zero_kernel<<<(NZERO4 + 255) / 256, 256, 0, stream>>>((int4*)degi);

  prep1_kernel<<<CNT_BLKS + BND_BLKS + PKWC_BLKS + PKWE_BLKS, 256, 0, stream>>>(
      dstp, degi, erank, batch, gstart, gend, conv_ws, Wp, enc_w, Wpe);
  blocksum_kernel<<<NSCAN, SCAN_BLK, 0, stream>>>(degi, bsum);
  offsets_kernel<<<NSCAN, SCAN_BLK, 0, stream>>>(degi, bsum, off, dis);
  fillenc_kernel<<<ENC_BLKS + FILL_BLKS, 256, 0, stream>>>(
      srcp, dstp, erank, off, dis, epack, x, Wpe, enc_b, ln_g, ln_b, Abf);

  for (int L = 0; L < 3; ++L) {
    convm_kernel<<<(NNODES + 63) / 64, 256, 0, stream>>>(Abf, Wp + (size_t)L * 16384, Bbf);
    gather_kernel<<<NNODES / 4, 256, 0, stream>>>(
        off, epack, dis, conv_bs + (size_t)L * HID, Bbf, Abf);
  }

  pool_kernel<<<NGRAPHS * PCHUNK, 128, 0, stream>>>(Abf, gstart, gend, sums);
  cls_kernel<<<NGRAPHS, 64, 0, stream>>>(sums, gstart, gend, c1w, c1b, c2w, c2b, out);
}

// Round 10
// 183.688 us; speedup vs baseline: 8.4281x; 1.1238x over previous
//
#include <hip/hip_runtime.h>

#define HID 128
#define DNODE 64
#define NNODES 50000
#define NEDGES 600000
#define NGRAPHS 64
#define LN_EPS 1e-5f
#define SCAN_BLK 256
#define NSCAN ((NNODES + SCAN_BLK - 1) / SCAN_BLK)   // 196

#define NZERO (NNODES + NGRAPHS * HID)    // ints to zero (degi+sums) = 58192
#define NZERO4 (NZERO / 4)                // 14548 int4 (exact)
#define Z_BLKS ((NZERO4 + 255) / 256)     // 57
#define PKWC_BLKS (3 * 16384 / 256)       // 192
#define PKWE_BLKS (8192 / 256)            // 32

#define ENC_BLKS ((NNODES + 63) / 64)     // 782
#define CNT_BLKS ((NEDGES + 255) / 256)   // 2344
#define BND_BLKS ((NNODES + 255) / 256)   // 196

#define CONV_BLKS ((NNODES + 63) / 64)    // 782
#define FILL_BLKS ((NEDGES + 255) / 256)  // 2344

#define GC_BLKS (NNODES / 16)             // 3125 (exact)

typedef __attribute__((ext_vector_type(8))) short bf16x8;
typedef __attribute__((ext_vector_type(8))) unsigned short u16x8;
typedef __attribute__((ext_vector_type(4))) float f32x4;

static __device__ __forceinline__ unsigned short f2bf(float f) {
  unsigned int u = __float_as_uint(f);
  u += 0x7fffu + ((u >> 16) & 1u);   // RNE
  return (unsigned short)(u >> 16);
}
static __device__ __forceinline__ float bf2f(unsigned short h) {
  return __uint_as_float(((unsigned int)h) << 16);
}

// ======== prep0: zero degi+sums | pack conv W | pack enc W ========
__global__ void __launch_bounds__(256) prep0_kernel(
    int4* __restrict__ zp, const float* __restrict__ W,
    unsigned short* __restrict__ Wp, const float* __restrict__ enc_w,
    unsigned short* __restrict__ Wpe) {
  int b = blockIdx.x;
  if (b < Z_BLKS) {
    int i = b * 256 + threadIdx.x;
    if (i < NZERO4) zp[i] = make_int4(0, 0, 0, 0);
  } else if (b < Z_BLKS + PKWC_BLKS) {
    int t = (b - Z_BLKS) * 256 + threadIdx.x;
    // Wp[layer][((nt*4+kk)*64+lane)*8+i] = W[layer][kk*32+(lane>>4)*8+i][nt*16+(lane&15)]
    int i = t & 7;
    int lane = (t >> 3) & 63;
    int kk = (t >> 9) & 3;
    int nt = (t >> 11) & 7;
    int layer = t >> 14;
    int k = kk * 32 + (lane >> 4) * 8 + i;
    int n = nt * 16 + (lane & 15);
    Wp[t] = f2bf(W[((size_t)layer * HID + k) * HID + n]);
  } else {
    int t = (b - Z_BLKS - PKWC_BLKS) * 256 + threadIdx.x;
    // Wpe[((nt*2+kk)*64+lane)*8+i] = enc_w[kk*32+(lane>>4)*8+i][nt*16+(lane&15)]
    int i = t & 7;
    int lane = (t >> 3) & 63;
    int kk = (t >> 9) & 1;
    int nt = (t >> 10) & 7;
    int k = kk * 32 + (lane >> 4) * 8 + i;
    int n = nt * 16 + (lane & 15);
    Wpe[t] = f2bf(enc_w[(size_t)k * HID + n]);
  }
}

// ======== prep1: MFMA encoder | edge-count+rank | graph-bounds ========
__global__ void __launch_bounds__(256) prep1_kernel(
    const float* __restrict__ x, const unsigned short* __restrict__ Wpe,
    const float* __restrict__ enc_b, const float* __restrict__ ln_g,
    const float* __restrict__ ln_b, unsigned short* __restrict__ Abf,
    const int* __restrict__ dst, int* __restrict__ degi, int* __restrict__ erank,
    const int* __restrict__ batch, int* __restrict__ gstart,
    int* __restrict__ gend) {
  __shared__ __align__(16) unsigned short tile[4][16][136];
  int blk = blockIdx.x;
  if (blk >= ENC_BLKS) {
    int b2 = blk - ENC_BLKS;
    if (b2 < CNT_BLKS) {
      int e = b2 * 256 + threadIdx.x;
      if (e < NEDGES) erank[e] = atomicAdd(&degi[dst[e]], 1);
    } else {
      int i = (b2 - CNT_BLKS) * 256 + threadIdx.x;
      if (i < NNODES) {
        int g = batch[i];
        if (i == 0 || batch[i - 1] != g) gstart[g] = i;
        if (i == NNODES - 1 || batch[i + 1] != g) gend[g] = i + 1;
      }
    }
    return;
  }
  int wave = threadIdx.x >> 6;
  int lane = threadIdx.x & 63;
  int l15 = lane & 15, h = lane >> 4;
  int base = blk * 64 + wave * 16;
  int row = base + l15;
  int rowc = row < NNODES ? row : NNODES - 1;
  const float* xr = x + (size_t)rowc * DNODE;
  bf16x8 a[2];
#pragma unroll
  for (int kk = 0; kk < 2; ++kk) {
    float4 p0 = *(const float4*)(xr + kk * 32 + h * 8);
    float4 p1 = *(const float4*)(xr + kk * 32 + h * 8 + 4);
    a[kk][0] = (short)f2bf(p0.x); a[kk][1] = (short)f2bf(p0.y);
    a[kk][2] = (short)f2bf(p0.z); a[kk][3] = (short)f2bf(p0.w);
    a[kk][4] = (short)f2bf(p1.x); a[kk][5] = (short)f2bf(p1.y);
    a[kk][6] = (short)f2bf(p1.z); a[kk][7] = (short)f2bf(p1.w);
  }
  f32x4 acc[8];
#pragma unroll
  for (int nt = 0; nt < 8; ++nt) acc[nt] = (f32x4)(0.f);
  const bf16x8* wp = (const bf16x8*)Wpe;
#pragma unroll
  for (int kk = 0; kk < 2; ++kk)
#pragma unroll
    for (int nt = 0; nt < 8; ++nt)
      acc[nt] = __builtin_amdgcn_mfma_f32_16x16x32_bf16(a[kk], wp[(nt * 2 + kk) * 64 + lane],
                                                        acc[nt], 0, 0, 0);
  float s[4] = {0.f, 0.f, 0.f, 0.f}, s2[4] = {0.f, 0.f, 0.f, 0.f};
#pragma unroll
  for (int nt = 0; nt < 8; ++nt) {
    float bcol = enc_b[nt * 16 + l15];
#pragma unroll
    for (int r = 0; r < 4; ++r) {
      float v = fmaxf(acc[nt][r] + bcol, 0.f);
      acc[nt][r] = v;
      s[r] += v;
      s2[r] = fmaf(v, v, s2[r]);
    }
  }
#pragma unroll
  for (int r = 0; r < 4; ++r) {
#pragma unroll
    for (int o = 1; o < 16; o <<= 1) {
      s[r] += __shfl_xor(s[r], o);
      s2[r] += __shfl_xor(s2[r], o);
    }
  }
  float mu[4], rstd[4];
#pragma unroll
  for (int r = 0; r < 4; ++r) {
    mu[r] = s[r] * (1.0f / HID);
    float var = s2[r] * (1.0f / HID) - mu[r] * mu[r];
    rstd[r] = rsqrtf(var + LN_EPS);
  }
#pragma unroll
  for (int nt = 0; nt < 8; ++nt) {
    float gcol = ln_g[nt * 16 + l15], bbcol = ln_b[nt * 16 + l15];
#pragma unroll
    for (int r = 0; r < 4; ++r)
      tile[wave][h * 4 + r][nt * 16 + l15] =
          f2bf((acc[nt][r] - mu[r]) * rstd[r] * gcol + bbcol);
  }
  __syncthreads();
  int trow = lane >> 2, tseg = lane & 3;
  int orow = base + trow;
  if (orow < NNODES) {
#pragma unroll
    for (int q = 0; q < 4; ++q) {
      u16x8 v = *(const u16x8*)&tile[wave][trow][tseg * 32 + q * 8];
      *(u16x8*)(Abf + (size_t)orow * HID + tseg * 32 + q * 8) = v;
    }
  }
}

// ======== scan step 1: per-block degree sums ========
__global__ void __launch_bounds__(SCAN_BLK) blocksum_kernel(
    const int* __restrict__ degi, int* __restrict__ bsum) {
  int i = blockIdx.x * SCAN_BLK + threadIdx.x;
  int v = (i < NNODES) ? degi[i] : 0;
#pragma unroll
  for (int off = 32; off; off >>= 1) v += __shfl_down(v, off);
  __shared__ int wsum[4];
  if ((threadIdx.x & 63) == 0) wsum[threadIdx.x >> 6] = v;
  __syncthreads();
  if (threadIdx.x == 0) bsum[blockIdx.x] = wsum[0] + wsum[1] + wsum[2] + wsum[3];
}

// ======== scan step 2: inline scan of bsums + per-element offsets ========
__global__ void __launch_bounds__(SCAN_BLK) offsets_kernel(
    const int* __restrict__ degi, const int* __restrict__ bsum,
    int* __restrict__ off, float* __restrict__ dis) {
  int b = blockIdx.x, t = threadIdx.x;
  __shared__ int sb[SCAN_BLK];
  __shared__ int s[SCAN_BLK];
  __shared__ int wred[4];
  sb[t] = (t < NSCAN) ? bsum[t] : 0;
  __syncthreads();
  int v = (t < b) ? sb[t] : 0;
#pragma unroll
  for (int o = 32; o; o >>= 1) v += __shfl_down(v, o);
  if ((t & 63) == 0) wred[t >> 6] = v;
  __syncthreads();
  int base = wred[0] + wred[1] + wred[2] + wred[3];
  int i = b * SCAN_BLK + t;
  int dv = (i < NNODES) ? degi[i] : 0;
  s[t] = dv;
  __syncthreads();
  for (int d = 1; d < SCAN_BLK; d <<= 1) {
    int x = (t >= d) ? s[t - d] : 0;
    __syncthreads();
    s[t] += x;
    __syncthreads();
  }
  if (i < NNODES) {
    int excl = s[t] - dv + base;
    off[i] = excl;
    dis[i] = rsqrtf((float)dv + 1.0f);
  }
  if (b == 0 && t == 0) off[NNODES] = NEDGES;
}

// ======== fillconv: conv0 via MFMA | atomic-free CSR fill ========
__global__ void __launch_bounds__(256) fillconv_kernel(
    const unsigned short* __restrict__ Abf, const unsigned short* __restrict__ Wp,
    unsigned short* __restrict__ Bbf, const int* __restrict__ src,
    const int* __restrict__ dst, const int* __restrict__ erank,
    const int* __restrict__ off, const float* __restrict__ dis,
    int2* __restrict__ epack) {
  __shared__ __align__(16) unsigned short tile[4][16][136];
  int blk = blockIdx.x;
  if (blk >= CONV_BLKS) {
    int e = (blk - CONV_BLKS) * 256 + threadIdx.x;
    if (e >= NEDGES) return;
    int d = dst[e];
    int sN = src[e];
    int r = erank[e];
    int2 v;
    v.x = sN;
    v.y = __float_as_int(dis[sN] * dis[d]);
    epack[off[d] + r] = v;
    return;
  }
  int wave = threadIdx.x >> 6;
  int lane = threadIdx.x & 63;
  int base = blk * 64 + wave * 16;
  int l15 = lane & 15, hi = lane >> 4;
  int row = base + l15;
  int rowc = row < NNODES ? row : NNODES - 1;
  bf16x8 a[4];
#pragma unroll
  for (int kk = 0; kk < 4; ++kk)
    a[kk] = *(const bf16x8*)(Abf + (size_t)rowc * HID + kk * 32 + hi * 8);
  f32x4 acc[8];
#pragma unroll
  for (int nt = 0; nt < 8; ++nt) acc[nt] = (f32x4)(0.f);
#pragma unroll
  for (int kk = 0; kk < 4; ++kk) {
#pragma unroll
    for (int nt = 0; nt < 8; ++nt) {
      bf16x8 w = *(const bf16x8*)(Wp + (((nt * 4 + kk) * 64 + lane) << 3));
      acc[nt] = __builtin_amdgcn_mfma_f32_16x16x32_bf16(a[kk], w, acc[nt], 0, 0, 0);
    }
  }
#pragma unroll
  for (int nt = 0; nt < 8; ++nt)
#pragma unroll
    for (int r = 0; r < 4; ++r)
      tile[wave][hi * 4 + r][nt * 16 + l15] = f2bf(acc[nt][r]);
  __syncthreads();
  int trow = lane >> 2, tseg = lane & 3;
  int orow = base + trow;
  if (orow < NNODES) {
#pragma unroll
    for (int s = 0; s < 4; ++s) {
      u16x8 v = *(const u16x8*)&tile[wave][trow][tseg * 32 + s * 8];
      *(u16x8*)(Bbf + (size_t)orow * HID + tseg * 32 + s * 8) = v;
    }
  }
}

// ======== gc: gather(layer L) fused with conv(layer L+1) ========
// 1024 thr = 16 waves; wave w gathers node blockIdx*16+w; A-tile in LDS;
// waves 0-7 then MFMA the 16x128 tile with next-layer W (nt = wave).
__global__ void __launch_bounds__(1024) gc_kernel(
    const int* __restrict__ off, const int2* __restrict__ epack,
    const float* __restrict__ dis, const float* __restrict__ bias,
    const unsigned short* __restrict__ Bin, const unsigned short* __restrict__ Wnext,
    unsigned short* __restrict__ Bout) {
  __shared__ __align__(16) unsigned short As[16][136];
  __shared__ __align__(16) unsigned short Bs[16][136];
  int w = threadIdx.x >> 6, lane = threadIdx.x & 63;
  int n = blockIdx.x * 16 + w;
  int slot = lane >> 4, p = lane & 15;
  int lo = off[n], hi = off[n + 1];
  float acc0[8], acc1[8];
#pragma unroll
  for (int i = 0; i < 8; ++i) { acc0[i] = 0.f; acc1[i] = 0.f; }
  int idx = lo + slot;
  for (; idx + 4 < hi; idx += 8) {
    int2 e0 = epack[idx];
    int2 e1 = epack[idx + 4];
    float w0 = __int_as_float(e0.y);
    float w1 = __int_as_float(e1.y);
    u16x8 v0 = *(const u16x8*)(Bin + (size_t)e0.x * HID + p * 8);
    u16x8 v1 = *(const u16x8*)(Bin + (size_t)e1.x * HID + p * 8);
#pragma unroll
    for (int i = 0; i < 8; ++i) acc0[i] = fmaf(bf2f(v0[i]), w0, acc0[i]);
#pragma unroll
    for (int i = 0; i < 8; ++i) acc1[i] = fmaf(bf2f(v1[i]), w1, acc1[i]);
  }
  if (idx < hi) {
    int2 e0 = epack[idx];
    float w0 = __int_as_float(e0.y);
    u16x8 v0 = *(const u16x8*)(Bin + (size_t)e0.x * HID + p * 8);
#pragma unroll
    for (int i = 0; i < 8; ++i) acc0[i] = fmaf(bf2f(v0[i]), w0, acc0[i]);
  }
#pragma unroll
  for (int i = 0; i < 8; ++i) {
    float a = acc0[i] + acc1[i];
    a += __shfl_xor(a, 16);
    a += __shfl_xor(a, 32);
    acc0[i] = a;
  }
  if (slot == 0) {
    float dn = dis[n];
    float d2 = dn * dn;
    u16x8 selfv = *(const u16x8*)(Bin + (size_t)n * HID + p * 8);
    float4 b0 = ((const float4*)bias)[p * 2];
    float4 b1 = ((const float4*)bias)[p * 2 + 1];
    float bb[8] = {b0.x, b0.y, b0.z, b0.w, b1.x, b1.y, b1.z, b1.w};
    u16x8 o;
#pragma unroll
    for (int i = 0; i < 8; ++i) {
      float v = fmaxf(fmaf(bf2f(selfv[i]), d2, bb[i]) + acc0[i], 0.f);
      o[i] = f2bf(v);
    }
    *(u16x8*)&As[w][p * 8] = o;   // row w of the block's A-tile
  }
  __syncthreads();
  // conv phase: wave w (<8) computes output cols [16w, 16w+16)
  if (w < 8) {
    bf16x8 a[4];
#pragma unroll
    for (int kk = 0; kk < 4; ++kk)
      a[kk] = *(const bf16x8*)&As[p][kk * 32 + slot * 8];  // p=row(lane&15), slot=lane>>4
    f32x4 acc = (f32x4)(0.f);
#pragma unroll
    for (int kk = 0; kk < 4; ++kk) {
      bf16x8 wf = *(const bf16x8*)(Wnext + (((w * 4 + kk) * 64 + lane) << 3));
      acc = __builtin_amdgcn_mfma_f32_16x16x32_bf16(a[kk], wf, acc, 0, 0, 0);
    }
#pragma unroll
    for (int r = 0; r < 4; ++r)
      Bs[slot * 4 + r][w * 16 + p] = f2bf(acc[r]);
  }
  __syncthreads();
  if (threadIdx.x < 256) {
    int row = threadIdx.x >> 4, seg = threadIdx.x & 15;
    *(u16x8*)(Bout + (size_t)(blockIdx.x * 16 + row) * HID + seg * 8) =
        *(const u16x8*)&Bs[row][seg * 8];
  }
}

// ======== g2pool: final gather fused with mean-pool partial sums ========
__global__ void __launch_bounds__(1024) g2pool_kernel(
    const int* __restrict__ off, const int2* __restrict__ epack,
    const float* __restrict__ dis, const float* __restrict__ bias,
    const unsigned short* __restrict__ Bin, const int* __restrict__ batch,
    float* __restrict__ sums) {
  __shared__ float Ps[16][132];
  __shared__ int bg[16];
  int w = threadIdx.x >> 6, lane = threadIdx.x & 63;
  int n = blockIdx.x * 16 + w;
  int slot = lane >> 4, p = lane & 15;
  int lo = off[n], hi = off[n + 1];
  float acc0[8], acc1[8];
#pragma unroll
  for (int i = 0; i < 8; ++i) { acc0[i] = 0.f; acc1[i] = 0.f; }
  int idx = lo + slot;
  for (; idx + 4 < hi; idx += 8) {
    int2 e0 = epack[idx];
    int2 e1 = epack[idx + 4];
    float w0 = __int_as_float(e0.y);
    float w1 = __int_as_float(e1.y);
    u16x8 v0 = *(const u16x8*)(Bin + (size_t)e0.x * HID + p * 8);
    u16x8 v1 = *(const u16x8*)(Bin + (size_t)e1.x * HID + p * 8);
#pragma unroll
    for (int i = 0; i < 8; ++i) acc0[i] = fmaf(bf2f(v0[i]), w0, acc0[i]);
#pragma unroll
    for (int i = 0; i < 8; ++i) acc1[i] = fmaf(bf2f(v1[i]), w1, acc1[i]);
  }
  if (idx < hi) {
    int2 e0 = epack[idx];
    float w0 = __int_as_float(e0.y);
    u16x8 v0 = *(const u16x8*)(Bin + (size_t)e0.x * HID + p * 8);
#pragma unroll
    for (int i = 0; i < 8; ++i) acc0[i] = fmaf(bf2f(v0[i]), w0, acc0[i]);
  }
#pragma unroll
  for (int i = 0; i < 8; ++i) {
    float a = acc0[i] + acc1[i];
    a += __shfl_xor(a, 16);
    a += __shfl_xor(a, 32);
    acc0[i] = a;
  }
  if (slot == 0) {
    float dn = dis[n];
    float d2 = dn * dn;
    u16x8 selfv = *(const u16x8*)(Bin + (size_t)n * HID + p * 8);
    float4 b0 = ((const float4*)bias)[p * 2];
    float4 b1 = ((const float4*)bias)[p * 2 + 1];
    float bb[8] = {b0.x, b0.y, b0.z, b0.w, b1.x, b1.y, b1.z, b1.w};
    float4 o0, o1;
    o0.x = fmaxf(fmaf(bf2f(selfv[0]), d2, bb[0]) + acc0[0], 0.f);
    o0.y = fmaxf(fmaf(bf2f(selfv[1]), d2, bb[1]) + acc0[1], 0.f);
    o0.z = fmaxf(fmaf(bf2f(selfv[2]), d2, bb[2]) + acc0[2], 0.f);
    o0.w = fmaxf(fmaf(bf2f(selfv[3]), d2, bb[3]) + acc0[3], 0.f);
    o1.x = fmaxf(fmaf(bf2f(selfv[4]), d2, bb[4]) + acc0[4], 0.f);
    o1.y = fmaxf(fmaf(bf2f(selfv[5]), d2, bb[5]) + acc0[5], 0.f);
    o1.z = fmaxf(fmaf(bf2f(selfv[6]), d2, bb[6]) + acc0[6], 0.f);
    o1.w = fmaxf(fmaf(bf2f(selfv[7]), d2, bb[7]) + acc0[7], 0.f);
    *(float4*)&Ps[w][p * 8] = o0;
    *(float4*)&Ps[w][p * 8 + 4] = o1;
  }
  if (threadIdx.x < 16) bg[threadIdx.x] = batch[blockIdx.x * 16 + threadIdx.x];
  __syncthreads();
  if (threadIdx.x < HID) {
    int j = threadIdx.x;
    float a = 0.f;
    int cur = bg[0];
    for (int r = 0; r < 16; ++r) {
      int g = bg[r];
      if (g != cur) { atomicAdd(&sums[cur * HID + j], a); a = 0.f; cur = g; }
      a += Ps[r][j];
    }
    atomicAdd(&sums[cur * HID + j], a);
  }
}

// ======== classifier head ========
__global__ void __launch_bounds__(64) cls_kernel(
    const float* __restrict__ sums, const int* __restrict__ gstart,
    const int* __restrict__ gend, const float* __restrict__ c1w,
    const float* __restrict__ c1b, const float* __restrict__ c2w,
    const float* __restrict__ c2b, float* __restrict__ out) {
  int g = blockIdx.x;
  int j = threadIdx.x;
  __shared__ float pooled[HID];
  float cnt = (float)(gend[g] - gstart[g]);
  float inv = 1.0f / fmaxf(cnt, 1.0f);
  pooled[j] = sums[g * HID + j] * inv;
  pooled[j + 64] = sums[g * HID + j + 64] * inv;
  __syncthreads();
  float s = c1b[j];
#pragma unroll 8
  for (int k = 0; k < HID; ++k) s = fmaf(pooled[k], c1w[k * 64 + j], s);
  s = fmaxf(s, 0.f) * c2w[j];
#pragma unroll
  for (int off = 32; off; off >>= 1) s += __shfl_down(s, off);
  if (j == 0) out[g] = s + c2b[0];
}

extern "C" void kernel_launch(void* const* d_in, const int* in_sizes, int n_in,
                              void* d_out, int out_size, void* d_ws, size_t ws_size,
                              hipStream_t stream) {
  const float* x = (const float*)d_in[0];
  const int* edge_index = (const int*)d_in[1];
  const int* batch = (const int*)d_in[3];
  const float* enc_w = (const float*)d_in[4];
  const float* enc_b = (const float*)d_in[5];
  const float* ln_g = (const float*)d_in[6];
  const float* ln_b = (const float*)d_in[7];
  const float* conv_ws = (const float*)d_in[10];
  const float* conv_bs = (const float*)d_in[11];
  const float* c1w = (const float*)d_in[12];
  const float* c1b = (const float*)d_in[13];
  const float* c2w = (const float*)d_in[14];
  const float* c2b = (const float*)d_in[15];
  float* out = (float*)d_out;

  unsigned short* Abf = (unsigned short*)d_ws;        // [NNODES*HID] bf16
  unsigned short* B1 = Abf + (size_t)NNODES * HID;    // [NNODES*HID] bf16
  unsigned short* B2 = B1 + (size_t)NNODES * HID;     // [NNODES*HID] bf16
  unsigned short* Wp = B2 + (size_t)NNODES * HID;     // [3*16384] bf16
  unsigned short* Wpe = Wp + 3 * 16384;               // [8192] bf16
  int2* epack = (int2*)(Wpe + 8192);                  // [NEDGES]
  int* erank = (int*)(epack + NEDGES);                // [NEDGES]
  int* degi = erank + NEDGES;                         // [NNODES]      --+ zeroed
  float* sums = (float*)(degi + NNODES);              // [NGRAPHS*HID] --+ together
  int* off = (int*)(sums + NGRAPHS * HID);            // [NNODES+1]
  float* dis = (float*)(off + NNODES + 1);            // [NNODES]
  int* bsum = (int*)(dis + NNODES);                   // [SCAN_BLK]
  int* gstart = bsum + SCAN_BLK;                      // [NGRAPHS]
  int* gend = gstart + NGRAPHS;                       // [NGRAPHS]

  const int* srcp = edge_index;
  const int* dstp = edge_index + NEDGES;

  prep0_kernel<<<Z_BLKS + PKWC_BLKS + PKWE_BLKS, 256, 0, stream>>>(
      (int4*)degi, conv_ws, Wp, enc_w, Wpe);
  prep1_kernel<<<ENC_BLKS + CNT_BLKS + BND_BLKS, 256, 0, stream>>>(
      x, Wpe, enc_b, ln_g, ln_b, Abf, dstp, degi, erank, batch, gstart, gend);
  blocksum_kernel<<<NSCAN, SCAN_BLK, 0, stream>>>(degi, bsum);
  offsets_kernel<<<NSCAN, SCAN_BLK, 0, stream>>>(degi, bsum, off, dis);
  fillconv_kernel<<<CONV_BLKS + FILL_BLKS, 256, 0, stream>>>(
      Abf, Wp, B1, srcp, dstp, erank, off, dis, epack);

  // layer0 gather + layer1 conv
  gc_kernel<<<GC_BLKS, 1024, 0, stream>>>(off, epack, dis, conv_bs, B1,
                                          Wp + (size_t)1 * 16384, B2);
  // layer1 gather + layer2 conv
  gc_kernel<<<GC_BLKS, 1024, 0, stream>>>(off, epack, dis, conv_bs + HID, B2,
                                          Wp + (size_t)2 * 16384, B1);
  // layer2 gather + pool
  g2pool_kernel<<<GC_BLKS, 1024, 0, stream>>>(off, epack, dis, conv_bs + 2 * HID,
                                              B1, batch, sums);
  cls_kernel<<<NGRAPHS, 64, 0, stream>>>(sums, gstart, gend, c1w, c1b, c2w, c2b, out);
}